// Round 3
// baseline (3143.148 us; speedup 1.0000x reference)
//
#include <hip/hip_runtime.h>
#include <hip/hip_bf16.h>

#define N_NODESC 100000
#define N_EDGESC 1600000
#define FEATC 64
#define HEADSC 8
#define BATCHC 64
#define MAXLENC 2048
#define NEG_SLOPE 0.2f

__device__ __forceinline__ float b2f(unsigned short u){
  union { unsigned u; float f; } c; c.u = ((unsigned)u) << 16; return c.f;
}
__device__ __forceinline__ unsigned short f2b(float f){
  union { float f; unsigned u; } c; c.f = f;
  unsigned r = c.u + 0x7fffu + ((c.u >> 16) & 1u);
  return (unsigned short)(r >> 16);
}
__device__ __forceinline__ float lrelu(float v){ return v > 0.f ? v : NEG_SLOPE * v; }
__device__ __forceinline__ int clampi(int v, int lo, int hi){
  return v < lo ? lo : (v > hi ? hi : v);
}
__device__ __forceinline__ void atomicMaxF(float* a, float v){
  if (v >= 0.f) atomicMax((int*)a, __float_as_int(v));
  else atomicMin((unsigned int*)a, __float_as_uint(v));
}
__device__ __forceinline__ void unpack8(uint4 v, float* o){
  o[0] = b2f((unsigned short)(v.x & 0xffff)); o[1] = b2f((unsigned short)(v.x >> 16));
  o[2] = b2f((unsigned short)(v.y & 0xffff)); o[3] = b2f((unsigned short)(v.y >> 16));
  o[4] = b2f((unsigned short)(v.z & 0xffff)); o[5] = b2f((unsigned short)(v.z >> 16));
  o[6] = b2f((unsigned short)(v.w & 0xffff)); o[7] = b2f((unsigned short)(v.w >> 16));
}

// K1: xw = x@W (stored bf16), a_src, a_dst, m = self-loop logit
__global__ __launch_bounds__(256) void k1_transform(
    const unsigned short* __restrict__ x, const unsigned short* __restrict__ W,
    const unsigned short* __restrict__ attS, const unsigned short* __restrict__ attD,
    unsigned short* __restrict__ xwb, float* __restrict__ a_src,
    float* __restrict__ a_dst, float* __restrict__ mmax)
{
  __shared__ float Wsf[64 * 64];
  __shared__ float as_s[64];
  __shared__ float ad_s[64];
  int t = threadIdx.x;
  for (int i = t; i < 4096; i += 256) Wsf[i] = b2f(W[i]);
  if (t < 64) { as_s[t] = b2f(attS[t]); ad_s[t] = b2f(attD[t]); }
  __syncthreads();

  int n = blockIdx.x * 256 + t;
  if (n >= N_NODESC) return;

  float acc[64];
  #pragma unroll
  for (int j = 0; j < 64; j++) acc[j] = 0.f;

  const uint4* xp = (const uint4*)(x + (size_t)n * 64);
  const float4* Ws4 = (const float4*)Wsf;
  for (int i = 0; i < 8; i++) {
    uint4 v = xp[i];
    float xv[8];
    unpack8(v, xv);
    const float4* Wrow = Ws4 + (size_t)(i * 8) * 16;
    #pragma unroll
    for (int u = 0; u < 8; u++) {
      float xk = xv[u];
      #pragma unroll
      for (int j = 0; j < 16; j++) {
        float4 w = Wrow[u * 16 + j];
        acc[j*4+0] += xk * w.x; acc[j*4+1] += xk * w.y;
        acc[j*4+2] += xk * w.z; acc[j*4+3] += xk * w.w;
      }
    }
  }

  // pack acc -> bf16, 8 x uint4 (64 bf16)
  uint4* xwp = (uint4*)(xwb + (size_t)n * 64);
  #pragma unroll
  for (int i = 0; i < 8; i++) {
    uint4 o;
    o.x = (unsigned)f2b(acc[i*8+0]) | ((unsigned)f2b(acc[i*8+1]) << 16);
    o.y = (unsigned)f2b(acc[i*8+2]) | ((unsigned)f2b(acc[i*8+3]) << 16);
    o.z = (unsigned)f2b(acc[i*8+4]) | ((unsigned)f2b(acc[i*8+5]) << 16);
    o.w = (unsigned)f2b(acc[i*8+6]) | ((unsigned)f2b(acc[i*8+7]) << 16);
    xwp[i] = o;
  }

  #pragma unroll
  for (int h = 0; h < 8; h++) {
    float sa = 0.f, sd = 0.f;
    #pragma unroll
    for (int c = 0; c < 8; c++) {
      sa += acc[h*8+c] * as_s[h*8+c];
      sd += acc[h*8+c] * ad_s[h*8+c];
    }
    a_src[n*8+h] = sa;
    a_dst[n*8+h] = sd;
    mmax[n*8+h] = lrelu(sa + sd);   // self-loop logit = segment-max init
  }
}

// K2: segment max over edges
__global__ __launch_bounds__(256) void k2_max(
    const int* __restrict__ ei, const float* __restrict__ a_src,
    const float* __restrict__ a_dst, float* __restrict__ mmax)
{
  int gid = blockIdx.x * 256 + threadIdx.x;
  if (gid >= N_EDGESC * HEADSC) return;
  int e = gid >> 3;
  int h = gid & 7;
  int src = clampi(ei[e], 0, N_NODESC - 1);
  int dst = clampi(ei[N_EDGESC + e], 0, N_NODESC - 1);
  float v = lrelu(a_src[src*8+h] + a_dst[dst*8+h]);
  atomicMaxF(&mmax[dst*8+h], v);
}

// K3: init denom and s with the self-loop term
__global__ __launch_bounds__(256) void k3_init(
    const float* __restrict__ a_src, const float* __restrict__ a_dst,
    const float* __restrict__ mmax, const unsigned short* __restrict__ xwb,
    float* __restrict__ denom, float* __restrict__ s)
{
  int gid = blockIdx.x * 256 + threadIdx.x;   // n*8+h
  if (gid >= N_NODESC * HEADSC) return;
  float e = lrelu(a_src[gid] + a_dst[gid]);
  float w = __expf(e - mmax[gid]);
  denom[gid] = w;
  uint4 v = ((const uint4*)xwb)[gid];
  float m[8];
  unpack8(v, m);
  float4* sp = (float4*)(s + (size_t)gid * 8);
  sp[0] = make_float4(w*m[0], w*m[1], w*m[2], w*m[3]);
  sp[1] = make_float4(w*m[4], w*m[5], w*m[6], w*m[7]);
}

// K4: accumulate exp-weighted messages + denominators
__global__ __launch_bounds__(256) void k4_accum(
    const int* __restrict__ ei, const float* __restrict__ a_src,
    const float* __restrict__ a_dst, const float* __restrict__ mmax,
    const unsigned short* __restrict__ xwb, float* __restrict__ denom,
    float* __restrict__ s)
{
  int gid = blockIdx.x * 256 + threadIdx.x;
  if (gid >= N_EDGESC * HEADSC) return;
  int e = gid >> 3;
  int h = gid & 7;
  int src = clampi(ei[e], 0, N_NODESC - 1);
  int dst = clampi(ei[N_EDGESC + e], 0, N_NODESC - 1);
  int di = dst*8 + h;
  float v = lrelu(a_src[src*8+h] + a_dst[di]);
  float ex = __expf(v - mmax[di]);
  atomicAdd(&denom[di], ex);
  uint4 mv = ((const uint4*)xwb)[src*8+h];
  float m[8];
  unpack8(mv, m);
  float* sb = s + (size_t)di * 8;
  atomicAdd(sb+0, ex*m[0]); atomicAdd(sb+1, ex*m[1]);
  atomicAdd(sb+2, ex*m[2]); atomicAdd(sb+3, ex*m[3]);
  atomicAdd(sb+4, ex*m[4]); atomicAdd(sb+5, ex*m[5]);
  atomicAdd(sb+6, ex*m[6]); atomicAdd(sb+7, ex*m[7]);
}

// K5: node_emb = relu(s/denom + bias) -> float32, IN-PLACE over s
__global__ __launch_bounds__(256) void k5_emb(
    float* __restrict__ s, const float* __restrict__ denom,
    const unsigned short* __restrict__ bias)
{
  int gid = blockIdx.x * 256 + threadIdx.x;   // n*64+f
  if (gid >= N_NODESC * FEATC) return;
  int f = gid & 63;
  int n = gid >> 6;
  int h = f >> 3;
  float v = s[gid] / denom[n*8+h] + b2f(bias[f]);
  s[gid] = v > 0.f ? v : 0.f;
}

// K6: padded gather (float32 out) + seq_lengths tail (float32)
__global__ __launch_bounds__(256) void k6_gather(
    const float* __restrict__ nemb, const int* __restrict__ traj,
    const int* __restrict__ lens, float* __restrict__ out)
{
  int gid = blockIdx.x * 256 + threadIdx.x;
  if (gid < BATCHC * MAXLENC * 16) {          // float4 chunks (64 f / 16 chunks per slot)
    int b = gid >> 15;        // 2048*16
    int rem = gid & 32767;
    int l = rem >> 4;
    int ch = rem & 15;
    int len = clampi(lens[b], 0, MAXLENC);
    float4 val = make_float4(0.f, 0.f, 0.f, 0.f);
    if (l < len) {
      int node = clampi(traj[b * MAXLENC + l], 0, N_NODESC - 1);
      val = ((const float4*)nemb)[(size_t)node * 16 + ch];
    }
    ((float4*)out)[gid] = val;
  }
  if (gid < BATCHC) {
    out[(size_t)BATCHC * MAXLENC * FEATC + gid] = (float)lens[gid];
  }
}

extern "C" void kernel_launch(void* const* d_in, const int* in_sizes, int n_in,
                              void* d_out, int out_size, void* d_ws, size_t ws_size,
                              hipStream_t stream) {
  const unsigned short* x    = (const unsigned short*)d_in[0];
  const unsigned short* W    = (const unsigned short*)d_in[1];
  const unsigned short* attS = (const unsigned short*)d_in[2];
  const unsigned short* attD = (const unsigned short*)d_in[3];
  const unsigned short* bias = (const unsigned short*)d_in[4];
  const int* ei   = (const int*)d_in[5];
  const int* traj = (const int*)d_in[6];
  const int* lens = (const int*)d_in[7];
  float* out = (float*)d_out;

  // workspace layout (51.2 MB):
  //   [0, 3.2M floats)   : xw as bf16 (6.4M ushort)
  //   [3.2M, 4.0M)       : a_src
  //   [4.0M, 4.8M)       : a_dst
  //   [4.8M, 5.6M)       : mmax
  //   [5.6M, 6.4M)       : denom
  //   [6.4M, 12.8M)      : s (fp32 accum -> node_emb fp32 in-place)
  float* F = (float*)d_ws;
  unsigned short* xwb = (unsigned short*)d_ws;
  float* a_src = F + 3200000;
  float* a_dst = F + 4000000;
  float* mmax  = F + 4800000;
  float* denom = F + 5600000;
  float* s     = F + 6400000;

  k1_transform<<<(N_NODESC + 255) / 256, 256, 0, stream>>>(x, W, attS, attD, xwb, a_src, a_dst, mmax);
  k2_max<<<(N_EDGESC * HEADSC + 255) / 256, 256, 0, stream>>>(ei, a_src, a_dst, mmax);
  k3_init<<<(N_NODESC * HEADSC + 255) / 256, 256, 0, stream>>>(a_src, a_dst, mmax, xwb, denom, s);
  k4_accum<<<(N_EDGESC * HEADSC + 255) / 256, 256, 0, stream>>>(ei, a_src, a_dst, mmax, xwb, denom, s);
  k5_emb<<<(N_NODESC * FEATC + 255) / 256, 256, 0, stream>>>(s, denom, bias);
  k6_gather<<<(BATCHC * MAXLENC * 16 + 255) / 256, 256, 0, stream>>>(s, traj, lens, out);
}

// Round 4
// 711.935 us; speedup vs baseline: 4.4149x; 4.4149x over previous
//
#include <hip/hip_runtime.h>
#include <hip/hip_bf16.h>

#define N_NODESC 100000
#define N_EDGESC 1600000
#define FEATC 64
#define HEADSC 8
#define BATCHC 64
#define MAXLENC 2048
#define NEG_SLOPE 0.2f

__device__ __forceinline__ float b2f(unsigned short u){
  union { unsigned u; float f; } c; c.u = ((unsigned)u) << 16; return c.f;
}
__device__ __forceinline__ unsigned short f2b(float f){
  union { float f; unsigned u; } c; c.f = f;
  unsigned r = c.u + 0x7fffu + ((c.u >> 16) & 1u);
  return (unsigned short)(r >> 16);
}
__device__ __forceinline__ float lrelu(float v){ return v > 0.f ? v : NEG_SLOPE * v; }
__device__ __forceinline__ int clampi(int v, int lo, int hi){
  return v < lo ? lo : (v > hi ? hi : v);
}
__device__ __forceinline__ void unpack8(uint4 v, float* o){
  o[0] = b2f((unsigned short)(v.x & 0xffff)); o[1] = b2f((unsigned short)(v.x >> 16));
  o[2] = b2f((unsigned short)(v.y & 0xffff)); o[3] = b2f((unsigned short)(v.y >> 16));
  o[4] = b2f((unsigned short)(v.z & 0xffff)); o[5] = b2f((unsigned short)(v.z >> 16));
  o[6] = b2f((unsigned short)(v.w & 0xffff)); o[7] = b2f((unsigned short)(v.w >> 16));
}

// ---- CSR build ----

__global__ __launch_bounds__(256) void k_zero(int* __restrict__ counts) {
  int i = blockIdx.x * 256 + threadIdx.x;
  if (i < N_NODESC) counts[i] = 0;
}

__global__ __launch_bounds__(256) void k_hist(const int* __restrict__ ei,
                                              int* __restrict__ counts) {
  int e = blockIdx.x * 256 + threadIdx.x;
  if (e >= N_EDGESC) return;
  int dst = clampi(ei[N_EDGESC + e], 0, N_NODESC - 1);
  atomicAdd(&counts[dst], 1);
}

// single block, 1024 threads: exclusive scan of 100k counts -> offsets, cursor
__global__ __launch_bounds__(1024) void k_scan(const int* __restrict__ counts,
                                               int* __restrict__ offsets,
                                               int* __restrict__ cursor) {
  __shared__ int part[1024];
  int t = threadIdx.x;
  const int CH = 98;                       // 98*1024 >= 100000
  int beg = t * CH;
  int end = beg + CH; if (end > N_NODESC) end = N_NODESC;
  int s = 0;
  for (int i = beg; i < end; i++) s += counts[i];
  part[t] = s;
  __syncthreads();
  for (int off = 1; off < 1024; off <<= 1) {
    int v = part[t];
    int add = (t >= off) ? part[t - off] : 0;
    __syncthreads();
    part[t] = v + add;
    __syncthreads();
  }
  int run = (t == 0) ? 0 : part[t - 1];
  for (int i = beg; i < end; i++) {
    offsets[i] = run; cursor[i] = run;
    run += counts[i];
  }
  if (t == 1023) offsets[N_NODESC] = part[1023];
}

__global__ __launch_bounds__(256) void k_scatter(const int* __restrict__ ei,
                                                 int* __restrict__ cursor,
                                                 int* __restrict__ srcSorted) {
  int e = blockIdx.x * 256 + threadIdx.x;
  if (e >= N_EDGESC) return;
  int src = clampi(ei[e], 0, N_NODESC - 1);
  int dst = clampi(ei[N_EDGESC + e], 0, N_NODESC - 1);
  int pos = atomicAdd(&cursor[dst], 1);
  srcSorted[pos] = src;
}

// ---- K1: xw = x@W (stored bf16), a_src, a_dst ----
__global__ __launch_bounds__(256) void k1_transform(
    const unsigned short* __restrict__ x, const unsigned short* __restrict__ W,
    const unsigned short* __restrict__ attS, const unsigned short* __restrict__ attD,
    unsigned short* __restrict__ xwb, float* __restrict__ a_src,
    float* __restrict__ a_dst)
{
  __shared__ float Wsf[64 * 64];
  __shared__ float as_s[64];
  __shared__ float ad_s[64];
  int t = threadIdx.x;
  for (int i = t; i < 4096; i += 256) Wsf[i] = b2f(W[i]);
  if (t < 64) { as_s[t] = b2f(attS[t]); ad_s[t] = b2f(attD[t]); }
  __syncthreads();

  int n = blockIdx.x * 256 + t;
  if (n >= N_NODESC) return;

  float acc[64];
  #pragma unroll
  for (int j = 0; j < 64; j++) acc[j] = 0.f;

  const uint4* xp = (const uint4*)(x + (size_t)n * 64);
  const float4* Ws4 = (const float4*)Wsf;
  for (int i = 0; i < 8; i++) {
    uint4 v = xp[i];
    float xv[8];
    unpack8(v, xv);
    const float4* Wrow = Ws4 + (size_t)(i * 8) * 16;
    #pragma unroll
    for (int u = 0; u < 8; u++) {
      float xk = xv[u];
      #pragma unroll
      for (int j = 0; j < 16; j++) {
        float4 w = Wrow[u * 16 + j];
        acc[j*4+0] += xk * w.x; acc[j*4+1] += xk * w.y;
        acc[j*4+2] += xk * w.z; acc[j*4+3] += xk * w.w;
      }
    }
  }

  uint4* xwp = (uint4*)(xwb + (size_t)n * 64);
  #pragma unroll
  for (int i = 0; i < 8; i++) {
    uint4 o;
    o.x = (unsigned)f2b(acc[i*8+0]) | ((unsigned)f2b(acc[i*8+1]) << 16);
    o.y = (unsigned)f2b(acc[i*8+2]) | ((unsigned)f2b(acc[i*8+3]) << 16);
    o.z = (unsigned)f2b(acc[i*8+4]) | ((unsigned)f2b(acc[i*8+5]) << 16);
    o.w = (unsigned)f2b(acc[i*8+6]) | ((unsigned)f2b(acc[i*8+7]) << 16);
    xwp[i] = o;
  }

  #pragma unroll
  for (int h = 0; h < 8; h++) {
    float sa = 0.f, sd = 0.f;
    #pragma unroll
    for (int c = 0; c < 8; c++) {
      sa += acc[h*8+c] * as_s[h*8+c];
      sd += acc[h*8+c] * ad_s[h*8+c];
    }
    a_src[n*8+h] = sa;
    a_dst[n*8+h] = sd;
  }
}

// ---- K_agg: one wave per dst node; online softmax over incoming edges.
// lane l: head h = l>>3, channel c = l&7. No atomics, no extra passes. ----
__global__ __launch_bounds__(256) void k_agg(
    const float* __restrict__ a_src, const float* __restrict__ a_dst,
    const unsigned short* __restrict__ xwb, const int* __restrict__ offsets,
    const int* __restrict__ srcSorted, const unsigned short* __restrict__ bias,
    float* __restrict__ nemb)
{
  int dst = ((blockIdx.x * 256 + threadIdx.x) >> 6);
  if (dst >= N_NODESC) return;
  int lane = threadIdx.x & 63;
  int h = lane >> 3;

  float adst = a_dst[dst * 8 + h];
  // self-loop initializes the online-softmax state
  float m   = lrelu(a_src[dst * 8 + h] + adst);
  float l   = 1.0f;
  float acc = b2f(xwb[(size_t)dst * 64 + lane]);

  int beg = offsets[dst], end = offsets[dst + 1];
  for (int i = beg; i < end; i++) {
    int src = srcSorted[i];
    float e  = lrelu(a_src[src * 8 + h] + adst);
    float xv = b2f(xwb[(size_t)src * 64 + lane]);
    float nm = fmaxf(m, e);
    float sc = __expf(m - nm);
    float w  = __expf(e - nm);
    acc = acc * sc + w * xv;
    l   = l * sc + w;
    m = nm;
  }

  float v = acc / l + b2f(bias[lane]);
  nemb[(size_t)dst * 64 + lane] = v > 0.f ? v : 0.f;
}

// ---- K6: padded gather (fp32 out) + seq_lengths tail ----
__global__ __launch_bounds__(256) void k6_gather(
    const float* __restrict__ nemb, const int* __restrict__ traj,
    const int* __restrict__ lens, float* __restrict__ out)
{
  int gid = blockIdx.x * 256 + threadIdx.x;
  if (gid < BATCHC * MAXLENC * 16) {          // float4 chunks
    int b = gid >> 15;
    int rem = gid & 32767;
    int l = rem >> 4;
    int ch = rem & 15;
    int len = clampi(lens[b], 0, MAXLENC);
    float4 val = make_float4(0.f, 0.f, 0.f, 0.f);
    if (l < len) {
      int node = clampi(traj[b * MAXLENC + l], 0, N_NODESC - 1);
      val = ((const float4*)nemb)[(size_t)node * 16 + ch];
    }
    ((float4*)out)[gid] = val;
  }
  if (gid < BATCHC) {
    out[(size_t)BATCHC * MAXLENC * FEATC + gid] = (float)lens[gid];
  }
}

extern "C" void kernel_launch(void* const* d_in, const int* in_sizes, int n_in,
                              void* d_out, int out_size, void* d_ws, size_t ws_size,
                              hipStream_t stream) {
  const unsigned short* x    = (const unsigned short*)d_in[0];
  const unsigned short* W    = (const unsigned short*)d_in[1];
  const unsigned short* attS = (const unsigned short*)d_in[2];
  const unsigned short* attD = (const unsigned short*)d_in[3];
  const unsigned short* bias = (const unsigned short*)d_in[4];
  const int* ei   = (const int*)d_in[5];
  const int* traj = (const int*)d_in[6];
  const int* lens = (const int*)d_in[7];
  float* out = (float*)d_out;

  // workspace (float units, 53.6 MB total):
  //  [0, 3.2M)      xw as bf16 (6.4M ushort)
  //  [3.2M, 4.0M)   a_src
  //  [4.0M, 4.8M)   a_dst
  //  [4.8M, 4.9M)   counts (int)
  //  [5.0M, 5.11M)  offsets (int, 100001)
  //  [5.2M, 5.3M)   cursor (int)
  //  [5.4M, 7.0M)   srcSorted (int, 1.6M)
  //  [7.0M, 13.4M)  nemb fp32
  float* F = (float*)d_ws;
  unsigned short* xwb = (unsigned short*)d_ws;
  float* a_src   = F + 3200000;
  float* a_dst   = F + 4000000;
  int* counts    = (int*)(F + 4800000);
  int* offsets   = (int*)(F + 5000000);
  int* cursor    = (int*)(F + 5200000);
  int* srcSorted = (int*)(F + 5400000);
  float* nemb    = F + 7000000;

  k_zero<<<(N_NODESC + 255) / 256, 256, 0, stream>>>(counts);
  k_hist<<<(N_EDGESC + 255) / 256, 256, 0, stream>>>(ei, counts);
  k_scan<<<1, 1024, 0, stream>>>(counts, offsets, cursor);
  k_scatter<<<(N_EDGESC + 255) / 256, 256, 0, stream>>>(ei, cursor, srcSorted);
  k1_transform<<<(N_NODESC + 255) / 256, 256, 0, stream>>>(x, W, attS, attD, xwb, a_src, a_dst);
  k_agg<<<(N_NODESC * 64 + 255) / 256, 256, 0, stream>>>(a_src, a_dst, xwb, offsets, srcSorted, bias, nemb);
  k6_gather<<<(BATCHC * MAXLENC * 16 + 255) / 256, 256, 0, stream>>>(nemb, traj, lens, out);
}

// Round 5
// 499.527 us; speedup vs baseline: 6.2922x; 1.4252x over previous
//
#include <hip/hip_runtime.h>
#include <hip/hip_bf16.h>

#define N_NODESC 100000
#define N_EDGESC 1600000
#define FEATC 64
#define HEADSC 8
#define BATCHC 64
#define MAXLENC 2048
#define NEG_SLOPE 0.2f

__device__ __forceinline__ float b2f(unsigned short u){
  union { unsigned u; float f; } c; c.u = ((unsigned)u) << 16; return c.f;
}
__device__ __forceinline__ unsigned short f2b(float f){
  union { float f; unsigned u; } c; c.f = f;
  unsigned r = c.u + 0x7fffu + ((c.u >> 16) & 1u);
  return (unsigned short)(r >> 16);
}
__device__ __forceinline__ float lrelu(float v){ return v > 0.f ? v : NEG_SLOPE * v; }
__device__ __forceinline__ int clampi(int v, int lo, int hi){
  return v < lo ? lo : (v > hi ? hi : v);
}
__device__ __forceinline__ void unpack8(uint4 v, float* o){
  o[0] = b2f((unsigned short)(v.x & 0xffff)); o[1] = b2f((unsigned short)(v.x >> 16));
  o[2] = b2f((unsigned short)(v.y & 0xffff)); o[3] = b2f((unsigned short)(v.y >> 16));
  o[4] = b2f((unsigned short)(v.z & 0xffff)); o[5] = b2f((unsigned short)(v.z >> 16));
  o[6] = b2f((unsigned short)(v.w & 0xffff)); o[7] = b2f((unsigned short)(v.w >> 16));
}

// ---- CSR build ----

__global__ __launch_bounds__(256) void k_zero(int* __restrict__ counts, int* __restrict__ total) {
  int i = blockIdx.x * 256 + threadIdx.x;
  if (i < N_NODESC) counts[i] = 0;
  if (i == 0) *total = 0;
}

__global__ __launch_bounds__(256) void k_hist(const int* __restrict__ ei,
                                              int* __restrict__ counts) {
  int e = blockIdx.x * 256 + threadIdx.x;
  if (e >= N_EDGESC) return;
  int dst = clampi(ei[N_EDGESC + e], 0, N_NODESC - 1);
  atomicAdd(&counts[dst], 1);
}

// Per-block LDS scan + atomic block base. Segment placement is NOT in node
// order (doesn't matter for CSR correctness: each node gets a unique region
// of size counts[n]; k_agg uses end = beg + counts[dst]).
__global__ __launch_bounds__(256) void k_offsets(const int* __restrict__ counts,
                                                 int* __restrict__ offsets,
                                                 int* __restrict__ cursor,
                                                 int* __restrict__ total) {
  __shared__ int sm[256];
  __shared__ int base;
  int t = threadIdx.x;
  int i = blockIdx.x * 256 + t;
  int c = (i < N_NODESC) ? counts[i] : 0;
  sm[t] = c;
  __syncthreads();
  #pragma unroll
  for (int off = 1; off < 256; off <<= 1) {
    int v = sm[t];
    int a = (t >= off) ? sm[t - off] : 0;
    __syncthreads();
    sm[t] = v + a;
    __syncthreads();
  }
  if (t == 255) base = atomicAdd(total, sm[255]);
  int excl = sm[t] - c;
  __syncthreads();
  if (i < N_NODESC) {
    int o = base + excl;
    offsets[i] = o;
    cursor[i] = o;
  }
}

__global__ __launch_bounds__(256) void k_scatter(const int* __restrict__ ei,
                                                 int* __restrict__ cursor,
                                                 int* __restrict__ srcSorted) {
  int e = blockIdx.x * 256 + threadIdx.x;
  if (e >= N_EDGESC) return;
  int src = clampi(ei[e], 0, N_NODESC - 1);
  int dst = clampi(ei[N_EDGESC + e], 0, N_NODESC - 1);
  int pos = atomicAdd(&cursor[dst], 1);
  srcSorted[pos] = src;
}

// ---- K1: xw = x@W (stored bf16), a_src, a_dst ----
__global__ __launch_bounds__(256) void k1_transform(
    const unsigned short* __restrict__ x, const unsigned short* __restrict__ W,
    const unsigned short* __restrict__ attS, const unsigned short* __restrict__ attD,
    unsigned short* __restrict__ xwb, float* __restrict__ a_src,
    float* __restrict__ a_dst)
{
  __shared__ float Wsf[64 * 64];
  __shared__ float as_s[64];
  __shared__ float ad_s[64];
  int t = threadIdx.x;
  for (int i = t; i < 4096; i += 256) Wsf[i] = b2f(W[i]);
  if (t < 64) { as_s[t] = b2f(attS[t]); ad_s[t] = b2f(attD[t]); }
  __syncthreads();

  int n = blockIdx.x * 256 + t;
  if (n >= N_NODESC) return;

  float acc[64];
  #pragma unroll
  for (int j = 0; j < 64; j++) acc[j] = 0.f;

  const uint4* xp = (const uint4*)(x + (size_t)n * 64);
  const float4* Ws4 = (const float4*)Wsf;
  for (int i = 0; i < 8; i++) {
    uint4 v = xp[i];
    float xv[8];
    unpack8(v, xv);
    const float4* Wrow = Ws4 + (size_t)(i * 8) * 16;
    #pragma unroll
    for (int u = 0; u < 8; u++) {
      float xk = xv[u];
      #pragma unroll
      for (int j = 0; j < 16; j++) {
        float4 w = Wrow[u * 16 + j];
        acc[j*4+0] += xk * w.x; acc[j*4+1] += xk * w.y;
        acc[j*4+2] += xk * w.z; acc[j*4+3] += xk * w.w;
      }
    }
  }

  uint4* xwp = (uint4*)(xwb + (size_t)n * 64);
  #pragma unroll
  for (int i = 0; i < 8; i++) {
    uint4 o;
    o.x = (unsigned)f2b(acc[i*8+0]) | ((unsigned)f2b(acc[i*8+1]) << 16);
    o.y = (unsigned)f2b(acc[i*8+2]) | ((unsigned)f2b(acc[i*8+3]) << 16);
    o.z = (unsigned)f2b(acc[i*8+4]) | ((unsigned)f2b(acc[i*8+5]) << 16);
    o.w = (unsigned)f2b(acc[i*8+6]) | ((unsigned)f2b(acc[i*8+7]) << 16);
    xwp[i] = o;
  }

  #pragma unroll
  for (int h = 0; h < 8; h++) {
    float sa = 0.f, sd = 0.f;
    #pragma unroll
    for (int c = 0; c < 8; c++) {
      sa += acc[h*8+c] * as_s[h*8+c];
      sd += acc[h*8+c] * ad_s[h*8+c];
    }
    a_src[n*8+h] = sa;
    a_dst[n*8+h] = sd;
  }
}

// ---- K_agg: one wave per dst node; online softmax; 1-iter prefetch ----
__global__ __launch_bounds__(256) void k_agg(
    const float* __restrict__ a_src, const float* __restrict__ a_dst,
    const unsigned short* __restrict__ xwb, const int* __restrict__ offsets,
    const int* __restrict__ counts, const int* __restrict__ srcSorted,
    const unsigned short* __restrict__ bias, float* __restrict__ nemb)
{
  int dst = ((blockIdx.x * 256 + threadIdx.x) >> 6);
  if (dst >= N_NODESC) return;
  int lane = threadIdx.x & 63;
  int h = lane >> 3;

  float adst = a_dst[dst * 8 + h];
  float m   = lrelu(a_src[dst * 8 + h] + adst);   // self-loop init
  float l   = 1.0f;
  float acc = b2f(xwb[(size_t)dst * 64 + lane]);

  int beg = offsets[dst];
  int end = beg + counts[dst];

  if (beg < end) {
    int   srcN = srcSorted[beg];
    float asN  = a_src[srcN * 8 + h];
    float xvN  = b2f(xwb[(size_t)srcN * 64 + lane]);
    for (int i = beg; i < end; i++) {
      float asC = asN, xvC = xvN;
      if (i + 1 < end) {
        int sn = srcSorted[i + 1];
        asN = a_src[sn * 8 + h];
        xvN = b2f(xwb[(size_t)sn * 64 + lane]);
      }
      float e  = lrelu(asC + adst);
      float nm = fmaxf(m, e);
      float sc = __expf(m - nm);
      float w  = __expf(e - nm);
      acc = acc * sc + w * xvC;
      l   = l * sc + w;
      m = nm;
    }
  }

  float v = acc / l + b2f(bias[lane]);
  nemb[(size_t)dst * 64 + lane] = v > 0.f ? v : 0.f;
}

// ---- K6: padded gather (fp32 out) + seq_lengths tail ----
__global__ __launch_bounds__(256) void k6_gather(
    const float* __restrict__ nemb, const int* __restrict__ traj,
    const int* __restrict__ lens, float* __restrict__ out)
{
  int gid = blockIdx.x * 256 + threadIdx.x;
  if (gid < BATCHC * MAXLENC * 16) {          // float4 chunks
    int b = gid >> 15;
    int rem = gid & 32767;
    int l = rem >> 4;
    int ch = rem & 15;
    int len = clampi(lens[b], 0, MAXLENC);
    float4 val = make_float4(0.f, 0.f, 0.f, 0.f);
    if (l < len) {
      int node = clampi(traj[b * MAXLENC + l], 0, N_NODESC - 1);
      val = ((const float4*)nemb)[(size_t)node * 16 + ch];
    }
    ((float4*)out)[gid] = val;
  }
  if (gid < BATCHC) {
    out[(size_t)BATCHC * MAXLENC * FEATC + gid] = (float)lens[gid];
  }
}

extern "C" void kernel_launch(void* const* d_in, const int* in_sizes, int n_in,
                              void* d_out, int out_size, void* d_ws, size_t ws_size,
                              hipStream_t stream) {
  const unsigned short* x    = (const unsigned short*)d_in[0];
  const unsigned short* W    = (const unsigned short*)d_in[1];
  const unsigned short* attS = (const unsigned short*)d_in[2];
  const unsigned short* attD = (const unsigned short*)d_in[3];
  const unsigned short* bias = (const unsigned short*)d_in[4];
  const int* ei   = (const int*)d_in[5];
  const int* traj = (const int*)d_in[6];
  const int* lens = (const int*)d_in[7];
  float* out = (float*)d_out;

  // workspace (float units, ~54 MB):
  //  [0, 3.2M)      xw as bf16 (6.4M ushort)
  //  [3.2M, 4.0M)   a_src
  //  [4.0M, 4.8M)   a_dst
  //  [4.8M, 4.9M)   counts (int)
  //  [5.0M, 5.1M)   offsets (int)
  //  [5.2M, 5.3M)   cursor (int)
  //  [5.3M, 5.31M)  total (int)
  //  [5.4M, 7.0M)   srcSorted (int, 1.6M)
  //  [7.0M, 13.4M)  nemb fp32
  float* F = (float*)d_ws;
  unsigned short* xwb = (unsigned short*)d_ws;
  float* a_src   = F + 3200000;
  float* a_dst   = F + 4000000;
  int* counts    = (int*)(F + 4800000);
  int* offsets   = (int*)(F + 5000000);
  int* cursor    = (int*)(F + 5200000);
  int* total     = (int*)(F + 5300000);
  int* srcSorted = (int*)(F + 5400000);
  float* nemb    = F + 7000000;

  k_zero<<<(N_NODESC + 255) / 256, 256, 0, stream>>>(counts, total);
  k_hist<<<(N_EDGESC + 255) / 256, 256, 0, stream>>>(ei, counts);
  k_offsets<<<(N_NODESC + 255) / 256, 256, 0, stream>>>(counts, offsets, cursor, total);
  k_scatter<<<(N_EDGESC + 255) / 256, 256, 0, stream>>>(ei, cursor, srcSorted);
  k1_transform<<<(N_NODESC + 255) / 256, 256, 0, stream>>>(x, W, attS, attD, xwb, a_src, a_dst);
  k_agg<<<(N_NODESC * 64 + 255) / 256, 256, 0, stream>>>(a_src, a_dst, xwb, offsets, counts, srcSorted, bias, nemb);
  k6_gather<<<(BATCHC * MAXLENC * 16 + 255) / 256, 256, 0, stream>>>(nemb, traj, lens, out);
}

// Round 6
// 401.469 us; speedup vs baseline: 7.8291x; 1.2442x over previous
//
#include <hip/hip_runtime.h>
#include <hip/hip_bf16.h>

#define N_NODESC 100000
#define N_EDGESC 1600000
#define FEATC 64
#define HEADSC 8
#define BATCHC 64
#define MAXLENC 2048
#define NEG_SLOPE 0.2f

__device__ __forceinline__ float b2f(unsigned short u){
  union { unsigned u; float f; } c; c.u = ((unsigned)u) << 16; return c.f;
}
__device__ __forceinline__ unsigned short f2b(float f){
  union { float f; unsigned u; } c; c.f = f;
  unsigned r = c.u + 0x7fffu + ((c.u >> 16) & 1u);
  return (unsigned short)(r >> 16);
}
__device__ __forceinline__ float lrelu(float v){ return v > 0.f ? v : NEG_SLOPE * v; }
__device__ __forceinline__ int clampi(int v, int lo, int hi){
  return v < lo ? lo : (v > hi ? hi : v);
}
__device__ __forceinline__ void unpack8(uint4 v, float* o){
  o[0] = b2f((unsigned short)(v.x & 0xffff)); o[1] = b2f((unsigned short)(v.x >> 16));
  o[2] = b2f((unsigned short)(v.y & 0xffff)); o[3] = b2f((unsigned short)(v.y >> 16));
  o[4] = b2f((unsigned short)(v.z & 0xffff)); o[5] = b2f((unsigned short)(v.z >> 16));
  o[6] = b2f((unsigned short)(v.w & 0xffff)); o[7] = b2f((unsigned short)(v.w >> 16));
}

// ---- CSR build ----

__global__ __launch_bounds__(256) void k_zero(int* __restrict__ counts, int* __restrict__ total) {
  int i = blockIdx.x * 256 + threadIdx.x;
  if (i < N_NODESC) counts[i] = 0;
  if (i == 0) *total = 0;
}

// 4 edges per thread via int4 (dst row is 16B-aligned: offset 6.4MB)
__global__ __launch_bounds__(256) void k_hist(const int* __restrict__ ei,
                                              int* __restrict__ counts) {
  int t = blockIdx.x * 256 + threadIdx.x;
  if (t >= N_EDGESC / 4) return;
  int4 d = ((const int4*)(ei + N_EDGESC))[t];
  atomicAdd(&counts[clampi(d.x, 0, N_NODESC - 1)], 1);
  atomicAdd(&counts[clampi(d.y, 0, N_NODESC - 1)], 1);
  atomicAdd(&counts[clampi(d.z, 0, N_NODESC - 1)], 1);
  atomicAdd(&counts[clampi(d.w, 0, N_NODESC - 1)], 1);
}

// Per-block LDS scan + atomic block base (segment placement not node-ordered;
// fine — each node gets a unique region, k_agg uses end = beg + counts[dst]).
__global__ __launch_bounds__(256) void k_offsets(const int* __restrict__ counts,
                                                 int* __restrict__ offsets,
                                                 int* __restrict__ cursor,
                                                 int* __restrict__ total) {
  __shared__ int sm[256];
  __shared__ int base;
  int t = threadIdx.x;
  int i = blockIdx.x * 256 + t;
  int c = (i < N_NODESC) ? counts[i] : 0;
  sm[t] = c;
  __syncthreads();
  #pragma unroll
  for (int off = 1; off < 256; off <<= 1) {
    int v = sm[t];
    int a = (t >= off) ? sm[t - off] : 0;
    __syncthreads();
    sm[t] = v + a;
    __syncthreads();
  }
  if (t == 255) base = atomicAdd(total, sm[255]);
  int excl = sm[t] - c;
  __syncthreads();
  if (i < N_NODESC) {
    int o = base + excl;
    offsets[i] = o;
    cursor[i] = o;
  }
}

// 2 edges per thread via int2
__global__ __launch_bounds__(256) void k_scatter(const int* __restrict__ ei,
                                                 int* __restrict__ cursor,
                                                 int* __restrict__ srcSorted) {
  int t = blockIdx.x * 256 + threadIdx.x;
  if (t >= N_EDGESC / 2) return;
  int2 s2 = ((const int2*)ei)[t];
  int2 d2 = ((const int2*)(ei + N_EDGESC))[t];
  int p0 = atomicAdd(&cursor[clampi(d2.x, 0, N_NODESC - 1)], 1);
  srcSorted[p0] = clampi(s2.x, 0, N_NODESC - 1);
  int p1 = atomicAdd(&cursor[clampi(d2.y, 0, N_NODESC - 1)], 1);
  srcSorted[p1] = clampi(s2.y, 0, N_NODESC - 1);
}

// ---- K1: xw = x@W (stored bf16), a_src, a_dst ----
__global__ __launch_bounds__(256) void k1_transform(
    const unsigned short* __restrict__ x, const unsigned short* __restrict__ W,
    const unsigned short* __restrict__ attS, const unsigned short* __restrict__ attD,
    unsigned short* __restrict__ xwb, float* __restrict__ a_src,
    float* __restrict__ a_dst)
{
  __shared__ float Wsf[64 * 64];
  __shared__ float as_s[64];
  __shared__ float ad_s[64];
  int t = threadIdx.x;
  for (int i = t; i < 4096; i += 256) Wsf[i] = b2f(W[i]);
  if (t < 64) { as_s[t] = b2f(attS[t]); ad_s[t] = b2f(attD[t]); }
  __syncthreads();

  int n = blockIdx.x * 256 + t;
  if (n >= N_NODESC) return;

  float acc[64];
  #pragma unroll
  for (int j = 0; j < 64; j++) acc[j] = 0.f;

  const uint4* xp = (const uint4*)(x + (size_t)n * 64);
  const float4* Ws4 = (const float4*)Wsf;
  for (int i = 0; i < 8; i++) {
    uint4 v = xp[i];
    float xv[8];
    unpack8(v, xv);
    const float4* Wrow = Ws4 + (size_t)(i * 8) * 16;
    #pragma unroll
    for (int u = 0; u < 8; u++) {
      float xk = xv[u];
      #pragma unroll
      for (int j = 0; j < 16; j++) {
        float4 w = Wrow[u * 16 + j];
        acc[j*4+0] += xk * w.x; acc[j*4+1] += xk * w.y;
        acc[j*4+2] += xk * w.z; acc[j*4+3] += xk * w.w;
      }
    }
  }

  uint4* xwp = (uint4*)(xwb + (size_t)n * 64);
  #pragma unroll
  for (int i = 0; i < 8; i++) {
    uint4 o;
    o.x = (unsigned)f2b(acc[i*8+0]) | ((unsigned)f2b(acc[i*8+1]) << 16);
    o.y = (unsigned)f2b(acc[i*8+2]) | ((unsigned)f2b(acc[i*8+3]) << 16);
    o.z = (unsigned)f2b(acc[i*8+4]) | ((unsigned)f2b(acc[i*8+5]) << 16);
    o.w = (unsigned)f2b(acc[i*8+6]) | ((unsigned)f2b(acc[i*8+7]) << 16);
    xwp[i] = o;
  }

  #pragma unroll
  for (int h = 0; h < 8; h++) {
    float sa = 0.f, sd = 0.f;
    #pragma unroll
    for (int c = 0; c < 8; c++) {
      sa += acc[h*8+c] * as_s[h*8+c];
      sd += acc[h*8+c] * ad_s[h*8+c];
    }
    a_src[n*8+h] = sa;
    a_dst[n*8+h] = sd;
  }
}

// ---- K_agg: one wave per dst; direct softmax (no max — logits bounded),
// predicated 8-wide edge batches for memory-level parallelism ----
__global__ __launch_bounds__(256) void k_agg(
    const float* __restrict__ a_src, const float* __restrict__ a_dst,
    const unsigned short* __restrict__ xwb, const int* __restrict__ offsets,
    const int* __restrict__ counts, const int* __restrict__ srcSorted,
    const unsigned short* __restrict__ bias, float* __restrict__ nemb)
{
  int dst = ((blockIdx.x * 256 + threadIdx.x) >> 6);
  if (dst >= N_NODESC) return;
  int lane = threadIdx.x & 63;
  int h = lane >> 3;

  float adst = a_dst[dst * 8 + h];
  // self-loop term
  float l   = __expf(lrelu(a_src[dst * 8 + h] + adst));
  float acc = l * b2f(xwb[(size_t)dst * 64 + lane]);

  int beg = offsets[dst];
  int end = beg + counts[dst];

  for (int i = beg; i < end; i += 8) {
    int   s[8];
    float a[8], xv[8];
    #pragma unroll
    for (int u = 0; u < 8; u++) {
      int idx = i + u;
      s[u] = srcSorted[idx < end ? idx : end - 1];
    }
    #pragma unroll
    for (int u = 0; u < 8; u++) a[u] = a_src[s[u] * 8 + h];
    #pragma unroll
    for (int u = 0; u < 8; u++) xv[u] = b2f(xwb[(size_t)s[u] * 64 + lane]);
    #pragma unroll
    for (int u = 0; u < 8; u++) {
      float w = (i + u < end) ? __expf(lrelu(a[u] + adst)) : 0.f;
      acc += w * xv[u];
      l   += w;
    }
  }

  float v = acc / l + b2f(bias[lane]);
  nemb[(size_t)dst * 64 + lane] = v > 0.f ? v : 0.f;
}

// ---- K6: padded gather (fp32 out) + seq_lengths tail ----
__global__ __launch_bounds__(256) void k6_gather(
    const float* __restrict__ nemb, const int* __restrict__ traj,
    const int* __restrict__ lens, float* __restrict__ out)
{
  int gid = blockIdx.x * 256 + threadIdx.x;
  if (gid < BATCHC * MAXLENC * 16) {          // float4 chunks
    int b = gid >> 15;
    int rem = gid & 32767;
    int l = rem >> 4;
    int ch = rem & 15;
    int len = clampi(lens[b], 0, MAXLENC);
    float4 val = make_float4(0.f, 0.f, 0.f, 0.f);
    if (l < len) {
      int node = clampi(traj[b * MAXLENC + l], 0, N_NODESC - 1);
      val = ((const float4*)nemb)[(size_t)node * 16 + ch];
    }
    ((float4*)out)[gid] = val;
  }
  if (gid < BATCHC) {
    out[(size_t)BATCHC * MAXLENC * FEATC + gid] = (float)lens[gid];
  }
}

extern "C" void kernel_launch(void* const* d_in, const int* in_sizes, int n_in,
                              void* d_out, int out_size, void* d_ws, size_t ws_size,
                              hipStream_t stream) {
  const unsigned short* x    = (const unsigned short*)d_in[0];
  const unsigned short* W    = (const unsigned short*)d_in[1];
  const unsigned short* attS = (const unsigned short*)d_in[2];
  const unsigned short* attD = (const unsigned short*)d_in[3];
  const unsigned short* bias = (const unsigned short*)d_in[4];
  const int* ei   = (const int*)d_in[5];
  const int* traj = (const int*)d_in[6];
  const int* lens = (const int*)d_in[7];
  float* out = (float*)d_out;

  // workspace (float units, ~54 MB):
  //  [0, 3.2M)      xw as bf16 (6.4M ushort)
  //  [3.2M, 4.0M)   a_src
  //  [4.0M, 4.8M)   a_dst
  //  [4.8M, 4.9M)   counts (int)
  //  [5.0M, 5.1M)   offsets (int)
  //  [5.2M, 5.3M)   cursor (int)
  //  [5.3M, 5.31M)  total (int)
  //  [5.4M, 7.0M)   srcSorted (int, 1.6M)
  //  [7.0M, 13.4M)  nemb fp32
  float* F = (float*)d_ws;
  unsigned short* xwb = (unsigned short*)d_ws;
  float* a_src   = F + 3200000;
  float* a_dst   = F + 4000000;
  int* counts    = (int*)(F + 4800000);
  int* offsets   = (int*)(F + 5000000);
  int* cursor    = (int*)(F + 5200000);
  int* total     = (int*)(F + 5300000);
  int* srcSorted = (int*)(F + 5400000);
  float* nemb    = F + 7000000;

  k_zero<<<(N_NODESC + 255) / 256, 256, 0, stream>>>(counts, total);
  k_hist<<<(N_EDGESC / 4 + 255) / 256, 256, 0, stream>>>(ei, counts);
  k_offsets<<<(N_NODESC + 255) / 256, 256, 0, stream>>>(counts, offsets, cursor, total);
  k_scatter<<<(N_EDGESC / 2 + 255) / 256, 256, 0, stream>>>(ei, cursor, srcSorted);
  k1_transform<<<(N_NODESC + 255) / 256, 256, 0, stream>>>(x, W, attS, attD, xwb, a_src, a_dst);
  k_agg<<<(N_NODESC * 64 + 255) / 256, 256, 0, stream>>>(a_src, a_dst, xwb, offsets, counts, srcSorted, bias, nemb);
  k6_gather<<<(BATCHC * MAXLENC * 16 + 255) / 256, 256, 0, stream>>>(nemb, traj, lens, out);
}

// Round 7
// 272.349 us; speedup vs baseline: 11.5409x; 1.4741x over previous
//
#include <hip/hip_runtime.h>
#include <hip/hip_bf16.h>

#define N_NODESC 100000
#define N_EDGESC 1600000
#define FEATC 64
#define HEADSC 8
#define BATCHC 64
#define MAXLENC 2048
#define NEG_SLOPE 0.2f
#define NBUCK 391          // ceil(100000/256) buckets of 256 dst nodes
#define P3_EDGES 4096      // edges per k_csort workgroup

__device__ __forceinline__ float b2f(unsigned short u){
  union { unsigned u; float f; } c; c.u = ((unsigned)u) << 16; return c.f;
}
__device__ __forceinline__ unsigned short f2b(float f){
  union { float f; unsigned u; } c; c.f = f;
  unsigned r = c.u + 0x7fffu + ((c.u >> 16) & 1u);
  return (unsigned short)(r >> 16);
}
__device__ __forceinline__ float lrelu(float v){ return v > 0.f ? v : NEG_SLOPE * v; }
__device__ __forceinline__ int clampi(int v, int lo, int hi){
  return v < lo ? lo : (v > hi ? hi : v);
}
__device__ __forceinline__ void unpack8(uint4 v, float* o){
  o[0] = b2f((unsigned short)(v.x & 0xffff)); o[1] = b2f((unsigned short)(v.x >> 16));
  o[2] = b2f((unsigned short)(v.y & 0xffff)); o[3] = b2f((unsigned short)(v.y >> 16));
  o[4] = b2f((unsigned short)(v.z & 0xffff)); o[5] = b2f((unsigned short)(v.z >> 16));
  o[6] = b2f((unsigned short)(v.w & 0xffff)); o[7] = b2f((unsigned short)(v.w >> 16));
}

// ---- CSR build: two-level counting sort (coarse 391 buckets -> per-node) ----

__global__ __launch_bounds__(256) void k_zero391(int* __restrict__ cc) {
  int t = threadIdx.x;
  for (int i = t; i < NBUCK; i += 256) cc[i] = 0;
}

// coarse histogram: LDS-private per wg, merged once
__global__ __launch_bounds__(256) void k_chist(const int* __restrict__ ei,
                                               int* __restrict__ cc) {
  __shared__ int h[NBUCK];
  int t = threadIdx.x;
  for (int i = t; i < NBUCK; i += 256) h[i] = 0;
  __syncthreads();
  int g = blockIdx.x * 256 + t;
  if (g < N_EDGESC / 4) {
    int4 d = ((const int4*)(ei + N_EDGESC))[g];
    atomicAdd(&h[clampi(d.x, 0, N_NODESC - 1) >> 8], 1);
    atomicAdd(&h[clampi(d.y, 0, N_NODESC - 1) >> 8], 1);
    atomicAdd(&h[clampi(d.z, 0, N_NODESC - 1) >> 8], 1);
    atomicAdd(&h[clampi(d.w, 0, N_NODESC - 1) >> 8], 1);
  }
  __syncthreads();
  for (int i = t; i < NBUCK; i += 256) if (h[i]) atomicAdd(&cc[i], h[i]);
}

// scan 391 bucket counts (single block)
__global__ __launch_bounds__(512) void k_cscan(const int* __restrict__ cc,
                                               int* __restrict__ bstart,
                                               int* __restrict__ gcur) {
  __shared__ int sm[512];
  int t = threadIdx.x;
  int c = (t < NBUCK) ? cc[t] : 0;
  sm[t] = c;
  __syncthreads();
  for (int off = 1; off < 512; off <<= 1) {
    int v = sm[t];
    int a = (t >= off) ? sm[t - off] : 0;
    __syncthreads();
    sm[t] = v + a;
    __syncthreads();
  }
  if (t < NBUCK) { int e = sm[t] - c; bstart[t] = e; gcur[t] = e; }
}

// coarse scatter: LDS counting-sort of 4096 edges by bucket, then contiguous
// per-bucket runs written with one global cursor atomic per (wg,bucket)
__global__ __launch_bounds__(512) void k_csort(const int* __restrict__ ei,
                                               int* __restrict__ gcur,
                                               int2* __restrict__ cs) {
  __shared__ int h[NBUCK], lst[NBUCK], lcur[NBUCK], gb[NBUCK];
  __shared__ int sc[512];
  __shared__ int2 sorted[P3_EDGES];
  int t = threadIdx.x;
  int base = blockIdx.x * P3_EDGES;
  for (int i = t; i < NBUCK; i += 512) h[i] = 0;
  __syncthreads();
  int2 ed[8]; int bk[8];
  #pragma unroll
  for (int k = 0; k < 8; k++) {
    int idx = base + k * 512 + t;
    bk[k] = -1;
    if (idx < N_EDGESC) {
      int s = clampi(ei[idx], 0, N_NODESC - 1);
      int d = clampi(ei[N_EDGESC + idx], 0, N_NODESC - 1);
      ed[k] = make_int2(s, d);
      bk[k] = d >> 8;
      atomicAdd(&h[bk[k]], 1);
    }
  }
  __syncthreads();
  sc[t] = (t < NBUCK) ? h[t] : 0;
  __syncthreads();
  for (int off = 1; off < 512; off <<= 1) {
    int v = sc[t];
    int a = (t >= off) ? sc[t - off] : 0;
    __syncthreads();
    sc[t] = v + a;
    __syncthreads();
  }
  if (t < NBUCK) {
    int ex = sc[t] - h[t];
    lst[t] = ex; lcur[t] = ex;
    if (h[t]) gb[t] = atomicAdd(&gcur[t], h[t]);
  }
  __syncthreads();
  #pragma unroll
  for (int k = 0; k < 8; k++) if (bk[k] >= 0) {
    int p = atomicAdd(&lcur[bk[k]], 1);
    sorted[p] = ed[k];
  }
  __syncthreads();
  int cnt = N_EDGESC - base; if (cnt > P3_EDGES) cnt = P3_EDGES;
  #pragma unroll
  for (int k = 0; k < 8; k++) {
    int i = k * 512 + t;
    if (i < cnt) {
      int2 e = sorted[i];
      int b = e.y >> 8;
      cs[gb[b] + (i - lst[b])] = e;
    }
  }
}

// fine: one wg per bucket; node histogram + scan -> offsets/counts, then
// scatter src within the bucket's L2-local window
__global__ __launch_bounds__(256) void k_fine(const int2* __restrict__ cs,
                                              const int* __restrict__ cc,
                                              const int* __restrict__ bstart,
                                              int* __restrict__ offsets,
                                              int* __restrict__ counts,
                                              int* __restrict__ srcSorted) {
  __shared__ int h[256], sc[256], lcur[256];
  int t = threadIdx.x, b = blockIdx.x;
  int base = bstart[b], cnt = cc[b];
  h[t] = 0;
  __syncthreads();
  for (int i = t; i < cnt; i += 256) atomicAdd(&h[cs[base + i].y & 255], 1);
  __syncthreads();
  sc[t] = h[t];
  __syncthreads();
  for (int off = 1; off < 256; off <<= 1) {
    int v = sc[t];
    int a = (t >= off) ? sc[t - off] : 0;
    __syncthreads();
    sc[t] = v + a;
    __syncthreads();
  }
  int ex = sc[t] - h[t];
  int n = (b << 8) + t;
  if (n < N_NODESC) { offsets[n] = base + ex; counts[n] = h[t]; }
  lcur[t] = base + ex;
  __syncthreads();
  for (int i = t; i < cnt; i += 256) {
    int2 e = cs[base + i];
    int p = atomicAdd(&lcur[e.y & 255], 1);
    srcSorted[p] = e.x;
  }
}

// ---- K1: xw = x@W (stored bf16), a_src, a_dst ----
__global__ __launch_bounds__(256) void k1_transform(
    const unsigned short* __restrict__ x, const unsigned short* __restrict__ W,
    const unsigned short* __restrict__ attS, const unsigned short* __restrict__ attD,
    unsigned short* __restrict__ xwb, float* __restrict__ a_src,
    float* __restrict__ a_dst)
{
  __shared__ float Wsf[64 * 64];
  __shared__ float as_s[64];
  __shared__ float ad_s[64];
  int t = threadIdx.x;
  for (int i = t; i < 4096; i += 256) Wsf[i] = b2f(W[i]);
  if (t < 64) { as_s[t] = b2f(attS[t]); ad_s[t] = b2f(attD[t]); }
  __syncthreads();

  int n = blockIdx.x * 256 + t;
  if (n >= N_NODESC) return;

  float acc[64];
  #pragma unroll
  for (int j = 0; j < 64; j++) acc[j] = 0.f;

  const uint4* xp = (const uint4*)(x + (size_t)n * 64);
  const float4* Ws4 = (const float4*)Wsf;
  for (int i = 0; i < 8; i++) {
    uint4 v = xp[i];
    float xv[8];
    unpack8(v, xv);
    const float4* Wrow = Ws4 + (size_t)(i * 8) * 16;
    #pragma unroll
    for (int u = 0; u < 8; u++) {
      float xk = xv[u];
      #pragma unroll
      for (int j = 0; j < 16; j++) {
        float4 w = Wrow[u * 16 + j];
        acc[j*4+0] += xk * w.x; acc[j*4+1] += xk * w.y;
        acc[j*4+2] += xk * w.z; acc[j*4+3] += xk * w.w;
      }
    }
  }

  uint4* xwp = (uint4*)(xwb + (size_t)n * 64);
  #pragma unroll
  for (int i = 0; i < 8; i++) {
    uint4 o;
    o.x = (unsigned)f2b(acc[i*8+0]) | ((unsigned)f2b(acc[i*8+1]) << 16);
    o.y = (unsigned)f2b(acc[i*8+2]) | ((unsigned)f2b(acc[i*8+3]) << 16);
    o.z = (unsigned)f2b(acc[i*8+4]) | ((unsigned)f2b(acc[i*8+5]) << 16);
    o.w = (unsigned)f2b(acc[i*8+6]) | ((unsigned)f2b(acc[i*8+7]) << 16);
    xwp[i] = o;
  }

  #pragma unroll
  for (int h = 0; h < 8; h++) {
    float sa = 0.f, sd = 0.f;
    #pragma unroll
    for (int c = 0; c < 8; c++) {
      sa += acc[h*8+c] * as_s[h*8+c];
      sd += acc[h*8+c] * ad_s[h*8+c];
    }
    a_src[n*8+h] = sa;
    a_dst[n*8+h] = sd;
  }
}

// ---- K_agg: one wave per dst; direct softmax (logits bounded, no max pass),
// predicated 8-wide edge batches for memory-level parallelism ----
__global__ __launch_bounds__(256) void k_agg(
    const float* __restrict__ a_src, const float* __restrict__ a_dst,
    const unsigned short* __restrict__ xwb, const int* __restrict__ offsets,
    const int* __restrict__ counts, const int* __restrict__ srcSorted,
    const unsigned short* __restrict__ bias, float* __restrict__ nemb)
{
  int dst = ((blockIdx.x * 256 + threadIdx.x) >> 6);
  if (dst >= N_NODESC) return;
  int lane = threadIdx.x & 63;
  int h = lane >> 3;

  float adst = a_dst[dst * 8 + h];
  float l   = __expf(lrelu(a_src[dst * 8 + h] + adst));   // self-loop
  float acc = l * b2f(xwb[(size_t)dst * 64 + lane]);

  int beg = offsets[dst];
  int end = beg + counts[dst];

  for (int i = beg; i < end; i += 8) {
    int   s[8];
    float a[8], xv[8];
    #pragma unroll
    for (int u = 0; u < 8; u++) {
      int idx = i + u;
      s[u] = srcSorted[idx < end ? idx : end - 1];
    }
    #pragma unroll
    for (int u = 0; u < 8; u++) a[u] = a_src[s[u] * 8 + h];
    #pragma unroll
    for (int u = 0; u < 8; u++) xv[u] = b2f(xwb[(size_t)s[u] * 64 + lane]);
    #pragma unroll
    for (int u = 0; u < 8; u++) {
      float w = (i + u < end) ? __expf(lrelu(a[u] + adst)) : 0.f;
      acc += w * xv[u];
      l   += w;
    }
  }

  float v = acc / l + b2f(bias[lane]);
  nemb[(size_t)dst * 64 + lane] = v > 0.f ? v : 0.f;
}

// ---- K6: padded gather (fp32 out) + seq_lengths tail ----
__global__ __launch_bounds__(256) void k6_gather(
    const float* __restrict__ nemb, const int* __restrict__ traj,
    const int* __restrict__ lens, float* __restrict__ out)
{
  int gid = blockIdx.x * 256 + threadIdx.x;
  if (gid < BATCHC * MAXLENC * 16) {          // float4 chunks
    int b = gid >> 15;
    int rem = gid & 32767;
    int l = rem >> 4;
    int ch = rem & 15;
    int len = clampi(lens[b], 0, MAXLENC);
    float4 val = make_float4(0.f, 0.f, 0.f, 0.f);
    if (l < len) {
      int node = clampi(traj[b * MAXLENC + l], 0, N_NODESC - 1);
      val = ((const float4*)nemb)[(size_t)node * 16 + ch];
    }
    ((float4*)out)[gid] = val;
  }
  if (gid < BATCHC) {
    out[(size_t)BATCHC * MAXLENC * FEATC + gid] = (float)lens[gid];
  }
}

extern "C" void kernel_launch(void* const* d_in, const int* in_sizes, int n_in,
                              void* d_out, int out_size, void* d_ws, size_t ws_size,
                              hipStream_t stream) {
  const unsigned short* x    = (const unsigned short*)d_in[0];
  const unsigned short* W    = (const unsigned short*)d_in[1];
  const unsigned short* attS = (const unsigned short*)d_in[2];
  const unsigned short* attD = (const unsigned short*)d_in[3];
  const unsigned short* bias = (const unsigned short*)d_in[4];
  const int* ei   = (const int*)d_in[5];
  const int* traj = (const int*)d_in[6];
  const int* lens = (const int*)d_in[7];
  float* out = (float*)d_out;

  // workspace (float units, 52.4 MB — within the proven 53.6 MB footprint):
  //  [0, 3.2M)        xw as bf16 (6.4M ushort)
  //  [3.2M, 4.0M)     a_src
  //  [4.0M, 4.8M)     a_dst
  //  [4.8M, 4.9M)     offsets (int)
  //  [4.9M, 5.0M)     counts (int)
  //  [5.0M, +512)     coarse counts (int, 391)
  //  [+512, +1024)    bucketStart
  //  [+1024, +1536)   gcursor
  //  [5.1M, 6.7M)     srcSorted (int, 1.6M)
  //  [6.7M, 9.9M)     coarseSorted (int2, 1.6M)  -- dead after k_fine
  //  [6.7M, 13.1M)    nemb fp32 (overlaps coarseSorted; written by k_agg)
  float* F = (float*)d_ws;
  unsigned short* xwb = (unsigned short*)d_ws;
  float* a_src   = F + 3200000;
  float* a_dst   = F + 4000000;
  int* offsets   = (int*)(F + 4800000);
  int* counts    = (int*)(F + 4900000);
  int* ccounts   = (int*)(F + 5000000);
  int* bstart    = (int*)(F + 5000000) + 512;
  int* gcur      = (int*)(F + 5000000) + 1024;
  int* srcSorted = (int*)(F + 5100000);
  int2* cs       = (int2*)(F + 6700000);
  float* nemb    = F + 6700000;

  k_zero391<<<1, 256, 0, stream>>>(ccounts);
  k_chist<<<(N_EDGESC / 4 + 255) / 256, 256, 0, stream>>>(ei, ccounts);
  k_cscan<<<1, 512, 0, stream>>>(ccounts, bstart, gcur);
  k_csort<<<(N_EDGESC + P3_EDGES - 1) / P3_EDGES, 512, 0, stream>>>(ei, gcur, cs);
  k_fine<<<NBUCK, 256, 0, stream>>>(cs, ccounts, bstart, offsets, counts, srcSorted);
  k1_transform<<<(N_NODESC + 255) / 256, 256, 0, stream>>>(x, W, attS, attD, xwb, a_src, a_dst);
  k_agg<<<(N_NODESC * 64 + 255) / 256, 256, 0, stream>>>(a_src, a_dst, xwb, offsets, counts, srcSorted, bias, nemb);
  k6_gather<<<(BATCHC * MAXLENC * 16 + 255) / 256, 256, 0, stream>>>(nemb, traj, lens, out);
}

// Round 8
// 237.148 us; speedup vs baseline: 13.2539x; 1.1484x over previous
//
#include <hip/hip_runtime.h>
#include <hip/hip_bf16.h>

#define N_NODESC 100000
#define N_EDGESC 1600000
#define FEATC 64
#define HEADSC 8
#define BATCHC 64
#define MAXLENC 2048
#define NEG_SLOPE 0.2f
#define NBUCK 391          // ceil(100000/256) buckets of 256 dst nodes
#define P3_EDGES 4096      // edges per k_csort workgroup

__device__ __forceinline__ float b2f(unsigned short u){
  union { unsigned u; float f; } c; c.u = ((unsigned)u) << 16; return c.f;
}
__device__ __forceinline__ unsigned short f2b(float f){
  union { float f; unsigned u; } c; c.f = f;
  unsigned r = c.u + 0x7fffu + ((c.u >> 16) & 1u);
  return (unsigned short)(r >> 16);
}
__device__ __forceinline__ int clampi(int v, int lo, int hi){
  return v < lo ? lo : (v > hi ? hi : v);
}
__device__ __forceinline__ void unpack8(uint4 v, float* o){
  o[0] = b2f((unsigned short)(v.x & 0xffff)); o[1] = b2f((unsigned short)(v.x >> 16));
  o[2] = b2f((unsigned short)(v.y & 0xffff)); o[3] = b2f((unsigned short)(v.y >> 16));
  o[4] = b2f((unsigned short)(v.z & 0xffff)); o[5] = b2f((unsigned short)(v.z >> 16));
  o[6] = b2f((unsigned short)(v.w & 0xffff)); o[7] = b2f((unsigned short)(v.w >> 16));
}

// ---- CSR build: two-level counting sort (unchanged from round 7) ----

__global__ __launch_bounds__(256) void k_zero391(int* __restrict__ cc) {
  int t = threadIdx.x;
  for (int i = t; i < NBUCK; i += 256) cc[i] = 0;
}

__global__ __launch_bounds__(256) void k_chist(const int* __restrict__ ei,
                                               int* __restrict__ cc) {
  __shared__ int h[NBUCK];
  int t = threadIdx.x;
  for (int i = t; i < NBUCK; i += 256) h[i] = 0;
  __syncthreads();
  int g = blockIdx.x * 256 + t;
  if (g < N_EDGESC / 4) {
    int4 d = ((const int4*)(ei + N_EDGESC))[g];
    atomicAdd(&h[clampi(d.x, 0, N_NODESC - 1) >> 8], 1);
    atomicAdd(&h[clampi(d.y, 0, N_NODESC - 1) >> 8], 1);
    atomicAdd(&h[clampi(d.z, 0, N_NODESC - 1) >> 8], 1);
    atomicAdd(&h[clampi(d.w, 0, N_NODESC - 1) >> 8], 1);
  }
  __syncthreads();
  for (int i = t; i < NBUCK; i += 256) if (h[i]) atomicAdd(&cc[i], h[i]);
}

__global__ __launch_bounds__(512) void k_cscan(const int* __restrict__ cc,
                                               int* __restrict__ bstart,
                                               int* __restrict__ gcur) {
  __shared__ int sm[512];
  int t = threadIdx.x;
  int c = (t < NBUCK) ? cc[t] : 0;
  sm[t] = c;
  __syncthreads();
  for (int off = 1; off < 512; off <<= 1) {
    int v = sm[t];
    int a = (t >= off) ? sm[t - off] : 0;
    __syncthreads();
    sm[t] = v + a;
    __syncthreads();
  }
  if (t < NBUCK) { int e = sm[t] - c; bstart[t] = e; gcur[t] = e; }
}

__global__ __launch_bounds__(512) void k_csort(const int* __restrict__ ei,
                                               int* __restrict__ gcur,
                                               int2* __restrict__ cs) {
  __shared__ int h[NBUCK], lst[NBUCK], lcur[NBUCK], gb[NBUCK];
  __shared__ int sc[512];
  __shared__ int2 sorted[P3_EDGES];
  int t = threadIdx.x;
  int base = blockIdx.x * P3_EDGES;
  for (int i = t; i < NBUCK; i += 512) h[i] = 0;
  __syncthreads();
  int2 ed[8]; int bk[8];
  #pragma unroll
  for (int k = 0; k < 8; k++) {
    int idx = base + k * 512 + t;
    bk[k] = -1;
    if (idx < N_EDGESC) {
      int s = clampi(ei[idx], 0, N_NODESC - 1);
      int d = clampi(ei[N_EDGESC + idx], 0, N_NODESC - 1);
      ed[k] = make_int2(s, d);
      bk[k] = d >> 8;
      atomicAdd(&h[bk[k]], 1);
    }
  }
  __syncthreads();
  sc[t] = (t < NBUCK) ? h[t] : 0;
  __syncthreads();
  for (int off = 1; off < 512; off <<= 1) {
    int v = sc[t];
    int a = (t >= off) ? sc[t - off] : 0;
    __syncthreads();
    sc[t] = v + a;
    __syncthreads();
  }
  if (t < NBUCK) {
    int ex = sc[t] - h[t];
    lst[t] = ex; lcur[t] = ex;
    if (h[t]) gb[t] = atomicAdd(&gcur[t], h[t]);
  }
  __syncthreads();
  #pragma unroll
  for (int k = 0; k < 8; k++) if (bk[k] >= 0) {
    int p = atomicAdd(&lcur[bk[k]], 1);
    sorted[p] = ed[k];
  }
  __syncthreads();
  int cnt = N_EDGESC - base; if (cnt > P3_EDGES) cnt = P3_EDGES;
  #pragma unroll
  for (int k = 0; k < 8; k++) {
    int i = k * 512 + t;
    if (i < cnt) {
      int2 e = sorted[i];
      int b = e.y >> 8;
      cs[gb[b] + (i - lst[b])] = e;
    }
  }
}

__global__ __launch_bounds__(256) void k_fine(const int2* __restrict__ cs,
                                              const int* __restrict__ cc,
                                              const int* __restrict__ bstart,
                                              int* __restrict__ offsets,
                                              int* __restrict__ counts,
                                              int* __restrict__ srcSorted) {
  __shared__ int h[256], sc[256], lcur[256];
  int t = threadIdx.x, b = blockIdx.x;
  int base = bstart[b], cnt = cc[b];
  h[t] = 0;
  __syncthreads();
  for (int i = t; i < cnt; i += 256) atomicAdd(&h[cs[base + i].y & 255], 1);
  __syncthreads();
  sc[t] = h[t];
  __syncthreads();
  for (int off = 1; off < 256; off <<= 1) {
    int v = sc[t];
    int a = (t >= off) ? sc[t - off] : 0;
    __syncthreads();
    sc[t] = v + a;
    __syncthreads();
  }
  int ex = sc[t] - h[t];
  int n = (b << 8) + t;
  if (n < N_NODESC) { offsets[n] = base + ex; counts[n] = h[t]; }
  lcur[t] = base + ex;
  __syncthreads();
  for (int i = t; i < cnt; i += 256) {
    int2 e = cs[base + i];
    int p = atomicAdd(&lcur[e.y & 255], 1);
    srcSorted[p] = e.x;
  }
}

// ---- K1: xw = x@W (bf16 out), a_src, a_dst.
// Retile: thread = (node-quad, 16-col group): each W LDS read feeds 4 nodes
// -> 256 ds_read_b128/thread instead of 1024. ----
__global__ __launch_bounds__(256) void k1_transform(
    const unsigned short* __restrict__ x, const unsigned short* __restrict__ W,
    const unsigned short* __restrict__ attS, const unsigned short* __restrict__ attD,
    unsigned short* __restrict__ xwb, float* __restrict__ a_src,
    float* __restrict__ a_dst)
{
  __shared__ float Wsf[64 * 64];
  __shared__ float as_s[64];
  __shared__ float ad_s[64];
  int t = threadIdx.x;
  for (int i = t; i < 4096; i += 256) Wsf[i] = b2f(W[i]);
  if (t < 64) { as_s[t] = b2f(attS[t]); ad_s[t] = b2f(attD[t]); }
  __syncthreads();

  int g    = t & 3;          // col group: cols g*16 .. g*16+15 (heads g*2, g*2+1)
  int slot = t >> 2;         // node quad slot
  int n0 = blockIdx.x * 256 + slot * 4;

  float acc[4][16];
  #pragma unroll
  for (int j = 0; j < 4; j++)
    #pragma unroll
    for (int c = 0; c < 16; c++) acc[j][c] = 0.f;

  const float4* Ws4 = (const float4*)Wsf;
  for (int i = 0; i < 8; i++) {            // K chunk of 8
    float xu[4][8];
    #pragma unroll
    for (int j = 0; j < 4; j++) {
      int n = n0 + j;
      uint4 v = make_uint4(0u,0u,0u,0u);
      if (n < N_NODESC) v = ((const uint4*)(x + (size_t)n * 64))[i];
      unpack8(v, xu[j]);
    }
    #pragma unroll
    for (int u = 0; u < 8; u++) {
      int k = i * 8 + u;
      float4 w0 = Ws4[k * 16 + g * 4 + 0];
      float4 w1 = Ws4[k * 16 + g * 4 + 1];
      float4 w2 = Ws4[k * 16 + g * 4 + 2];
      float4 w3 = Ws4[k * 16 + g * 4 + 3];
      #pragma unroll
      for (int j = 0; j < 4; j++) {
        float xk = xu[j][u];
        acc[j][ 0] += xk * w0.x; acc[j][ 1] += xk * w0.y;
        acc[j][ 2] += xk * w0.z; acc[j][ 3] += xk * w0.w;
        acc[j][ 4] += xk * w1.x; acc[j][ 5] += xk * w1.y;
        acc[j][ 6] += xk * w1.z; acc[j][ 7] += xk * w1.w;
        acc[j][ 8] += xk * w2.x; acc[j][ 9] += xk * w2.y;
        acc[j][10] += xk * w2.z; acc[j][11] += xk * w2.w;
        acc[j][12] += xk * w3.x; acc[j][13] += xk * w3.y;
        acc[j][14] += xk * w3.z; acc[j][15] += xk * w3.w;
      }
    }
  }

  #pragma unroll
  for (int j = 0; j < 4; j++) {
    int n = n0 + j;
    if (n >= N_NODESC) break;
    uint4 o0, o1;
    o0.x = (unsigned)f2b(acc[j][ 0]) | ((unsigned)f2b(acc[j][ 1]) << 16);
    o0.y = (unsigned)f2b(acc[j][ 2]) | ((unsigned)f2b(acc[j][ 3]) << 16);
    o0.z = (unsigned)f2b(acc[j][ 4]) | ((unsigned)f2b(acc[j][ 5]) << 16);
    o0.w = (unsigned)f2b(acc[j][ 6]) | ((unsigned)f2b(acc[j][ 7]) << 16);
    o1.x = (unsigned)f2b(acc[j][ 8]) | ((unsigned)f2b(acc[j][ 9]) << 16);
    o1.y = (unsigned)f2b(acc[j][10]) | ((unsigned)f2b(acc[j][11]) << 16);
    o1.z = (unsigned)f2b(acc[j][12]) | ((unsigned)f2b(acc[j][13]) << 16);
    o1.w = (unsigned)f2b(acc[j][14]) | ((unsigned)f2b(acc[j][15]) << 16);
    uint4* dp = (uint4*)(xwb + (size_t)n * 64 + g * 16);
    dp[0] = o0; dp[1] = o1;
    #pragma unroll
    for (int hl = 0; hl < 2; hl++) {
      int h = g * 2 + hl;
      float sa = 0.f, sd = 0.f;
      #pragma unroll
      for (int c = 0; c < 8; c++) {
        sa += acc[j][hl * 8 + c] * as_s[h * 8 + c];
        sd += acc[j][hl * 8 + c] * ad_s[h * 8 + c];
      }
      a_src[n * 8 + h] = sa;
      a_dst[n * 8 + h] = sd;
    }
  }
}

// ---- K_agg: one wave per dst. Batches of 8 edges.
// w computed in (edge,head) lane layout: ONE exp per wave per 8 edges;
// broadcast back to (head,chan) layout via shfl; src row base via readlane.
__global__ __launch_bounds__(256) void k_agg(
    const float* __restrict__ a_src, const float* __restrict__ a_dst,
    const unsigned short* __restrict__ xwb, const int* __restrict__ offsets,
    const int* __restrict__ counts, const int* __restrict__ srcSorted,
    const unsigned short* __restrict__ bias, float* __restrict__ nemb)
{
  int dst = ((blockIdx.x * 256 + threadIdx.x) >> 6);   // grid exact: 25000 blocks
  int l = threadIdx.x & 63;
  int H  = l >> 3;   // acc layout: head
  int hw = l & 7;    // w layout: head   (E = l>>3 edge slot)

  // self-loop (acc layout)
  float zs = a_src[dst * 8 + H] + a_dst[dst * 8 + H];
  float selfw = __expf(fmaxf(zs, 0.2f * zs));
  float acc = selfw * b2f(xwb[(size_t)dst * 64 + l]);

  float adW = a_dst[dst * 8 + hw];   // w layout

  int beg = offsets[dst];
  int end = beg + counts[dst];
  float lw = 0.f;

  for (int i = beg; i < end; i += 8) {
    int idx = i + H;                       // edge slot E == H bits
    bool valid = idx < end;
    int sv = srcSorted[valid ? idx : end - 1];
    float av = a_src[sv * 8 + hw];
    float z = av + adW;
    float w = __expf(fmaxf(z, 0.2f * z));
    w = valid ? w : 0.f;
    lw += w;
    #pragma unroll
    for (int e = 0; e < 8; e++) {
      int   se = __builtin_amdgcn_readlane(sv, e * 8);   // src of edge e (SGPR)
      float wb = __shfl(w, (e << 3) + H, 64);            // w[e][H]
      float xv = b2f(xwb[(size_t)se * 64 + l]);
      acc += wb * xv;
    }
  }

  // denom: sum lw over edge-slices (lanes differing in bits 3..5)
  lw += __shfl_xor(lw, 8, 64);
  lw += __shfl_xor(lw, 16, 64);
  lw += __shfl_xor(lw, 32, 64);
  float denom = selfw + __shfl(lw, H, 64);   // lane H holds head H sum

  float v = acc / denom + b2f(bias[l]);
  nemb[(size_t)dst * 64 + l] = v > 0.f ? v : 0.f;
}

// ---- K6: padded gather (fp32 out) + seq_lengths tail ----
__global__ __launch_bounds__(256) void k6_gather(
    const float* __restrict__ nemb, const int* __restrict__ traj,
    const int* __restrict__ lens, float* __restrict__ out)
{
  int gid = blockIdx.x * 256 + threadIdx.x;
  if (gid < BATCHC * MAXLENC * 16) {          // float4 chunks
    int b = gid >> 15;
    int rem = gid & 32767;
    int l = rem >> 4;
    int ch = rem & 15;
    int len = clampi(lens[b], 0, MAXLENC);
    float4 val = make_float4(0.f, 0.f, 0.f, 0.f);
    if (l < len) {
      int node = clampi(traj[b * MAXLENC + l], 0, N_NODESC - 1);
      val = ((const float4*)nemb)[(size_t)node * 16 + ch];
    }
    ((float4*)out)[gid] = val;
  }
  if (gid < BATCHC) {
    out[(size_t)BATCHC * MAXLENC * FEATC + gid] = (float)lens[gid];
  }
}

extern "C" void kernel_launch(void* const* d_in, const int* in_sizes, int n_in,
                              void* d_out, int out_size, void* d_ws, size_t ws_size,
                              hipStream_t stream) {
  const unsigned short* x    = (const unsigned short*)d_in[0];
  const unsigned short* W    = (const unsigned short*)d_in[1];
  const unsigned short* attS = (const unsigned short*)d_in[2];
  const unsigned short* attD = (const unsigned short*)d_in[3];
  const unsigned short* bias = (const unsigned short*)d_in[4];
  const int* ei   = (const int*)d_in[5];
  const int* traj = (const int*)d_in[6];
  const int* lens = (const int*)d_in[7];
  float* out = (float*)d_out;

  // workspace layout identical to round 7 (proven 52.4 MB)
  float* F = (float*)d_ws;
  unsigned short* xwb = (unsigned short*)d_ws;
  float* a_src   = F + 3200000;
  float* a_dst   = F + 4000000;
  int* offsets   = (int*)(F + 4800000);
  int* counts    = (int*)(F + 4900000);
  int* ccounts   = (int*)(F + 5000000);
  int* bstart    = (int*)(F + 5000000) + 512;
  int* gcur      = (int*)(F + 5000000) + 1024;
  int* srcSorted = (int*)(F + 5100000);
  int2* cs       = (int2*)(F + 6700000);
  float* nemb    = F + 6700000;

  k_zero391<<<1, 256, 0, stream>>>(ccounts);
  k_chist<<<(N_EDGESC / 4 + 255) / 256, 256, 0, stream>>>(ei, ccounts);
  k_cscan<<<1, 512, 0, stream>>>(ccounts, bstart, gcur);
  k_csort<<<(N_EDGESC + P3_EDGES - 1) / P3_EDGES, 512, 0, stream>>>(ei, gcur, cs);
  k_fine<<<NBUCK, 256, 0, stream>>>(cs, ccounts, bstart, offsets, counts, srcSorted);
  k1_transform<<<(N_NODESC + 255) / 256, 256, 0, stream>>>(x, W, attS, attD, xwb, a_src, a_dst);
  k_agg<<<(N_NODESC * 64) / 256, 256, 0, stream>>>(a_src, a_dst, xwb, offsets, counts, srcSorted, bias, nemb);
  k6_gather<<<(BATCHC * MAXLENC * 16 + 255) / 256, 256, 0, stream>>>(nemb, traj, lens, out);
}

// Round 9
// 235.123 us; speedup vs baseline: 13.3681x; 1.0086x over previous
//
#include <hip/hip_runtime.h>
#include <hip/hip_bf16.h>
#include <hip/hip_fp8.h>

#define N_NODESC 100000
#define N_EDGESC 1600000
#define FEATC 64
#define HEADSC 8
#define BATCHC 64
#define MAXLENC 2048
#define NEG_SLOPE 0.2f
#define NBUCK 391          // ceil(100000/256) buckets of 256 dst nodes
#define P3_EDGES 4096      // edges per k_csort workgroup

__device__ __forceinline__ float b2f(unsigned short u){
  union { unsigned u; float f; } c; c.u = ((unsigned)u) << 16; return c.f;
}
__device__ __forceinline__ int clampi(int v, int lo, int hi){
  return v < lo ? lo : (v > hi ? hi : v);
}
__device__ __forceinline__ void unpack8(uint4 v, float* o){
  o[0] = b2f((unsigned short)(v.x & 0xffff)); o[1] = b2f((unsigned short)(v.x >> 16));
  o[2] = b2f((unsigned short)(v.y & 0xffff)); o[3] = b2f((unsigned short)(v.y >> 16));
  o[4] = b2f((unsigned short)(v.z & 0xffff)); o[5] = b2f((unsigned short)(v.z >> 16));
  o[6] = b2f((unsigned short)(v.w & 0xffff)); o[7] = b2f((unsigned short)(v.w >> 16));
}
__device__ __forceinline__ float fp8tof(unsigned char b){
  __hip_fp8_e4m3 q; q.__x = (__hip_fp8_storage_t)b; return (float)q;
}

// ---- CSR build: two-level counting sort; cs packed src|dstLocal<<17 ----

__global__ __launch_bounds__(256) void k_zero391(int* __restrict__ cc) {
  int t = threadIdx.x;
  for (int i = t; i < NBUCK; i += 256) cc[i] = 0;
}

__global__ __launch_bounds__(256) void k_chist(const int* __restrict__ ei,
                                               int* __restrict__ cc) {
  __shared__ int h[NBUCK];
  int t = threadIdx.x;
  for (int i = t; i < NBUCK; i += 256) h[i] = 0;
  __syncthreads();
  int g = blockIdx.x * 256 + t;
  if (g < N_EDGESC / 4) {
    int4 d = ((const int4*)(ei + N_EDGESC))[g];
    atomicAdd(&h[clampi(d.x, 0, N_NODESC - 1) >> 8], 1);
    atomicAdd(&h[clampi(d.y, 0, N_NODESC - 1) >> 8], 1);
    atomicAdd(&h[clampi(d.z, 0, N_NODESC - 1) >> 8], 1);
    atomicAdd(&h[clampi(d.w, 0, N_NODESC - 1) >> 8], 1);
  }
  __syncthreads();
  for (int i = t; i < NBUCK; i += 256) if (h[i]) atomicAdd(&cc[i], h[i]);
}

__global__ __launch_bounds__(512) void k_cscan(const int* __restrict__ cc,
                                               int* __restrict__ bstart,
                                               int* __restrict__ gcur) {
  __shared__ int sm[512];
  int t = threadIdx.x;
  int c = (t < NBUCK) ? cc[t] : 0;
  sm[t] = c;
  __syncthreads();
  for (int off = 1; off < 512; off <<= 1) {
    int v = sm[t];
    int a = (t >= off) ? sm[t - off] : 0;
    __syncthreads();
    sm[t] = v + a;
    __syncthreads();
  }
  if (t < NBUCK) { int e = sm[t] - c; bstart[t] = e; gcur[t] = e; }
}

__global__ __launch_bounds__(512) void k_csort(const int* __restrict__ ei,
                                               int* __restrict__ gcur,
                                               unsigned* __restrict__ cs) {
  __shared__ int h[NBUCK], lst[NBUCK], lcur[NBUCK], gb[NBUCK];
  __shared__ int sc[512];
  __shared__ unsigned sorted[P3_EDGES];
  __shared__ unsigned short sbk[P3_EDGES];
  int t = threadIdx.x;
  int base = blockIdx.x * P3_EDGES;
  for (int i = t; i < NBUCK; i += 512) h[i] = 0;
  __syncthreads();
  unsigned pk[8]; int bk[8];
  #pragma unroll
  for (int k = 0; k < 8; k++) {
    int idx = base + k * 512 + t;
    bk[k] = -1;
    if (idx < N_EDGESC) {
      int s = clampi(ei[idx], 0, N_NODESC - 1);
      int d = clampi(ei[N_EDGESC + idx], 0, N_NODESC - 1);
      pk[k] = (unsigned)s | ((unsigned)(d & 255) << 17);
      bk[k] = d >> 8;
      atomicAdd(&h[bk[k]], 1);
    }
  }
  __syncthreads();
  sc[t] = (t < NBUCK) ? h[t] : 0;
  __syncthreads();
  for (int off = 1; off < 512; off <<= 1) {
    int v = sc[t];
    int a = (t >= off) ? sc[t - off] : 0;
    __syncthreads();
    sc[t] = v + a;
    __syncthreads();
  }
  if (t < NBUCK) {
    int ex = sc[t] - h[t];
    lst[t] = ex; lcur[t] = ex;
    if (h[t]) gb[t] = atomicAdd(&gcur[t], h[t]);
  }
  __syncthreads();
  #pragma unroll
  for (int k = 0; k < 8; k++) if (bk[k] >= 0) {
    int p = atomicAdd(&lcur[bk[k]], 1);
    sorted[p] = pk[k];
    sbk[p] = (unsigned short)bk[k];
  }
  __syncthreads();
  int cnt = N_EDGESC - base; if (cnt > P3_EDGES) cnt = P3_EDGES;
  #pragma unroll
  for (int k = 0; k < 8; k++) {
    int i = k * 512 + t;
    if (i < cnt) {
      int b = sbk[i];
      cs[gb[b] + (i - lst[b])] = sorted[i];
    }
  }
}

__global__ __launch_bounds__(256) void k_fine(const unsigned* __restrict__ cs,
                                              const int* __restrict__ cc,
                                              const int* __restrict__ bstart,
                                              int* __restrict__ offsets,
                                              int* __restrict__ counts,
                                              int* __restrict__ srcSorted) {
  __shared__ int h[256], sc[256], lcur[256];
  int t = threadIdx.x, b = blockIdx.x;
  int base = bstart[b], cnt = cc[b];
  h[t] = 0;
  __syncthreads();
  for (int i = t; i < cnt; i += 256) atomicAdd(&h[cs[base + i] >> 17], 1);
  __syncthreads();
  sc[t] = h[t];
  __syncthreads();
  for (int off = 1; off < 256; off <<= 1) {
    int v = sc[t];
    int a = (t >= off) ? sc[t - off] : 0;
    __syncthreads();
    sc[t] = v + a;
    __syncthreads();
  }
  int ex = sc[t] - h[t];
  int n = (b << 8) + t;
  if (n < N_NODESC) { offsets[n] = base + ex; counts[n] = h[t]; }
  lcur[t] = base + ex;
  __syncthreads();
  for (int i = t; i < cnt; i += 256) {
    unsigned e = cs[base + i];
    int p = atomicAdd(&lcur[e >> 17], 1);
    srcSorted[p] = (int)(e & 0x1FFFFu);
  }
}

// ---- K1: xw = x@W -> fp8 e4m3 table; a_src, a_dst in fp32 ----
__global__ __launch_bounds__(256) void k1_transform(
    const unsigned short* __restrict__ x, const unsigned short* __restrict__ W,
    const unsigned short* __restrict__ attS, const unsigned short* __restrict__ attD,
    unsigned char* __restrict__ xw8, float* __restrict__ a_src,
    float* __restrict__ a_dst)
{
  __shared__ float Wsf[64 * 64];
  __shared__ float as_s[64];
  __shared__ float ad_s[64];
  int t = threadIdx.x;
  for (int i = t; i < 4096; i += 256) Wsf[i] = b2f(W[i]);
  if (t < 64) { as_s[t] = b2f(attS[t]); ad_s[t] = b2f(attD[t]); }
  __syncthreads();

  int g    = t & 3;          // col group: cols g*16..g*16+15 (heads g*2, g*2+1)
  int slot = t >> 2;         // node quad slot
  int n0 = blockIdx.x * 256 + slot * 4;

  float acc[4][16];
  #pragma unroll
  for (int j = 0; j < 4; j++)
    #pragma unroll
    for (int c = 0; c < 16; c++) acc[j][c] = 0.f;

  const float4* Ws4 = (const float4*)Wsf;
  for (int i = 0; i < 8; i++) {
    float xu[4][8];
    #pragma unroll
    for (int j = 0; j < 4; j++) {
      int n = n0 + j;
      uint4 v = make_uint4(0u,0u,0u,0u);
      if (n < N_NODESC) v = ((const uint4*)(x + (size_t)n * 64))[i];
      unpack8(v, xu[j]);
    }
    #pragma unroll
    for (int u = 0; u < 8; u++) {
      int k = i * 8 + u;
      float4 w0 = Ws4[k * 16 + g * 4 + 0];
      float4 w1 = Ws4[k * 16 + g * 4 + 1];
      float4 w2 = Ws4[k * 16 + g * 4 + 2];
      float4 w3 = Ws4[k * 16 + g * 4 + 3];
      #pragma unroll
      for (int j = 0; j < 4; j++) {
        float xk = xu[j][u];
        acc[j][ 0] += xk * w0.x; acc[j][ 1] += xk * w0.y;
        acc[j][ 2] += xk * w0.z; acc[j][ 3] += xk * w0.w;
        acc[j][ 4] += xk * w1.x; acc[j][ 5] += xk * w1.y;
        acc[j][ 6] += xk * w1.z; acc[j][ 7] += xk * w1.w;
        acc[j][ 8] += xk * w2.x; acc[j][ 9] += xk * w2.y;
        acc[j][10] += xk * w2.z; acc[j][11] += xk * w2.w;
        acc[j][12] += xk * w3.x; acc[j][13] += xk * w3.y;
        acc[j][14] += xk * w3.z; acc[j][15] += xk * w3.w;
      }
    }
  }

  #pragma unroll
  for (int j = 0; j < 4; j++) {
    int n = n0 + j;
    if (n >= N_NODESC) break;
    union { unsigned u[4]; unsigned char b[16]; } pk;
    #pragma unroll
    for (int c = 0; c < 16; c++)
      pk.b[c] = (unsigned char)__hip_fp8_e4m3(acc[j][c]).__x;
    uint4 o; o.x = pk.u[0]; o.y = pk.u[1]; o.z = pk.u[2]; o.w = pk.u[3];
    *((uint4*)(xw8 + (size_t)n * 64 + g * 16)) = o;

    #pragma unroll
    for (int hl = 0; hl < 2; hl++) {
      int h = g * 2 + hl;
      float sa = 0.f, sd = 0.f;
      #pragma unroll
      for (int c = 0; c < 8; c++) {
        sa += acc[j][hl * 8 + c] * as_s[h * 8 + c];
        sd += acc[j][hl * 8 + c] * ad_s[h * 8 + c];
      }
      a_src[n * 8 + h] = sa;
      a_dst[n * 8 + h] = sd;
    }
  }
}

// ---- K_agg: one wave per dst; fp8 message gather (64 B/row = one L2 line);
// w in (edge,head) lane layout (one exp per wave per 8 edges), shfl broadcast.
__global__ __launch_bounds__(256) void k_agg(
    const float* __restrict__ a_src, const float* __restrict__ a_dst,
    const unsigned char* __restrict__ xw8, const int* __restrict__ offsets,
    const int* __restrict__ counts, const int* __restrict__ srcSorted,
    const unsigned short* __restrict__ bias, float* __restrict__ nemb)
{
  int dst = ((blockIdx.x * 256 + threadIdx.x) >> 6);
  int l = threadIdx.x & 63;
  int H  = l >> 3;   // acc layout: head
  int hw = l & 7;    // w layout: head (edge slot = l>>3)

  float zs = a_src[dst * 8 + H] + a_dst[dst * 8 + H];
  float selfw = __expf(fmaxf(zs, 0.2f * zs));
  float acc = selfw * fp8tof(xw8[(size_t)dst * 64 + l]);

  float adW = a_dst[dst * 8 + hw];

  int beg = offsets[dst];
  int end = beg + counts[dst];
  float lw = 0.f;

  for (int i = beg; i < end; i += 8) {
    int idx = i + H;
    bool valid = idx < end;
    int sv = srcSorted[valid ? idx : end - 1];
    float av = a_src[sv * 8 + hw];
    float z = av + adW;
    float w = __expf(fmaxf(z, 0.2f * z));
    w = valid ? w : 0.f;
    lw += w;
    #pragma unroll
    for (int e = 0; e < 8; e++) {
      int   se = __builtin_amdgcn_readlane(sv, e * 8);
      float wb = __shfl(w, (e << 3) + H, 64);
      float xv = fp8tof(xw8[(size_t)se * 64 + l]);
      acc += wb * xv;
    }
  }

  lw += __shfl_xor(lw, 8, 64);
  lw += __shfl_xor(lw, 16, 64);
  lw += __shfl_xor(lw, 32, 64);
  float denom = selfw + __shfl(lw, H, 64);

  float v = acc / denom + b2f(bias[l]);
  nemb[(size_t)dst * 64 + l] = v > 0.f ? v : 0.f;
}

// ---- K6: padded gather (fp32 out) + seq_lengths tail ----
__global__ __launch_bounds__(256) void k6_gather(
    const float* __restrict__ nemb, const int* __restrict__ traj,
    const int* __restrict__ lens, float* __restrict__ out)
{
  int gid = blockIdx.x * 256 + threadIdx.x;
  if (gid < BATCHC * MAXLENC * 16) {
    int b = gid >> 15;
    int rem = gid & 32767;
    int l = rem >> 4;
    int ch = rem & 15;
    int len = clampi(lens[b], 0, MAXLENC);
    float4 val = make_float4(0.f, 0.f, 0.f, 0.f);
    if (l < len) {
      int node = clampi(traj[b * MAXLENC + l], 0, N_NODESC - 1);
      val = ((const float4*)nemb)[(size_t)node * 16 + ch];
    }
    ((float4*)out)[gid] = val;
  }
  if (gid < BATCHC) {
    out[(size_t)BATCHC * MAXLENC * FEATC + gid] = (float)lens[gid];
  }
}

extern "C" void kernel_launch(void* const* d_in, const int* in_sizes, int n_in,
                              void* d_out, int out_size, void* d_ws, size_t ws_size,
                              hipStream_t stream) {
  const unsigned short* x    = (const unsigned short*)d_in[0];
  const unsigned short* W    = (const unsigned short*)d_in[1];
  const unsigned short* attS = (const unsigned short*)d_in[2];
  const unsigned short* attD = (const unsigned short*)d_in[3];
  const unsigned short* bias = (const unsigned short*)d_in[4];
  const int* ei   = (const int*)d_in[5];
  const int* traj = (const int*)d_in[6];
  const int* lens = (const int*)d_in[7];
  float* out = (float*)d_out;

  // workspace (float units, max 13.1M floats = 52.4 MB — proven size):
  //  [0, 1.6M)        xw fp8 (6.4M bytes)
  //  [3.2M, 4.0M)     a_src
  //  [4.0M, 4.8M)     a_dst
  //  [4.8M, 4.9M)     offsets (int)
  //  [4.9M, 5.0M)     counts (int)
  //  [5.0M, +1536)    ccounts / bstart / gcur
  //  [5.1M, 6.7M)     srcSorted (int, 1.6M)
  //  [6.7M, 7.1M)     cs (packed uint, 1.6M)  -- dead after k_fine
  //  [6.7M, 13.1M)    nemb fp32 (overlaps cs; written by k_agg)
  float* F = (float*)d_ws;
  unsigned char* xw8 = (unsigned char*)d_ws;
  float* a_src   = F + 3200000;
  float* a_dst   = F + 4000000;
  int* offsets   = (int*)(F + 4800000);
  int* counts    = (int*)(F + 4900000);
  int* ccounts   = (int*)(F + 5000000);
  int* bstart    = (int*)(F + 5000000) + 512;
  int* gcur      = (int*)(F + 5000000) + 1024;
  int* srcSorted = (int*)(F + 5100000);
  unsigned* cs   = (unsigned*)(F + 6700000);
  float* nemb    = F + 6700000;

  k_zero391<<<1, 256, 0, stream>>>(ccounts);
  k_chist<<<(N_EDGESC / 4 + 255) / 256, 256, 0, stream>>>(ei, ccounts);
  k_cscan<<<1, 512, 0, stream>>>(ccounts, bstart, gcur);
  k_csort<<<(N_EDGESC + P3_EDGES - 1) / P3_EDGES, 512, 0, stream>>>(ei, gcur, cs);
  k_fine<<<NBUCK, 256, 0, stream>>>(cs, ccounts, bstart, offsets, counts, srcSorted);
  k1_transform<<<(N_NODESC + 255) / 256, 256, 0, stream>>>(x, W, attS, attD, xw8, a_src, a_dst);
  k_agg<<<(N_NODESC * 64) / 256, 256, 0, stream>>>(a_src, a_dst, xw8, offsets, counts, srcSorted, bias, nemb);
  k6_gather<<<(BATCHC * MAXLENC * 16 + 255) / 256, 256, 0, stream>>>(nemb, traj, lens, out);
}

// Round 10
// 219.191 us; speedup vs baseline: 14.3398x; 1.0727x over previous
//
#include <hip/hip_runtime.h>
#include <hip/hip_bf16.h>
#include <hip/hip_fp8.h>

#define N_NODESC 100000
#define N_EDGESC 1600000
#define FEATC 64
#define HEADSC 8
#define BATCHC 64
#define MAXLENC 2048
#define NBUCK 500          // 500 buckets x exactly 200 dst nodes
#define BSZ 200
#define CAP 6144           // LDS edge capacity per bucket (mean 3200, sigma ~57)
#define P3_EDGES 4096      // edges per k_csort workgroup

__device__ __forceinline__ float b2f(unsigned short u){
  union { unsigned u; float f; } c; c.u = ((unsigned)u) << 16; return c.f;
}
__device__ __forceinline__ unsigned short f2b(float f){
  union { float f; unsigned u; } c; c.f = f;
  unsigned r = c.u + 0x7fffu + ((c.u >> 16) & 1u);
  return (unsigned short)(r >> 16);
}
__device__ __forceinline__ int clampi(int v, int lo, int hi){
  return v < lo ? lo : (v > hi ? hi : v);
}
__device__ __forceinline__ void unpack8(uint4 v, float* o){
  o[0] = b2f((unsigned short)(v.x & 0xffff)); o[1] = b2f((unsigned short)(v.x >> 16));
  o[2] = b2f((unsigned short)(v.y & 0xffff)); o[3] = b2f((unsigned short)(v.y >> 16));
  o[4] = b2f((unsigned short)(v.z & 0xffff)); o[5] = b2f((unsigned short)(v.z >> 16));
  o[6] = b2f((unsigned short)(v.w & 0xffff)); o[7] = b2f((unsigned short)(v.w >> 16));
}
__device__ __forceinline__ float fp8tof(unsigned char b){
  __hip_fp8_e4m3 q; q.__x = (__hip_fp8_storage_t)b; return (float)q;
}

// ---- coarse histogram (500 bins) ----
__global__ __launch_bounds__(256) void k_chist(const int* __restrict__ ei,
                                               int* __restrict__ cc) {
  __shared__ int h[NBUCK];
  int t = threadIdx.x;
  for (int i = t; i < NBUCK; i += 256) h[i] = 0;
  __syncthreads();
  int g = blockIdx.x * 256 + t;
  if (g < N_EDGESC / 4) {
    int4 d = ((const int4*)(ei + N_EDGESC))[g];
    atomicAdd(&h[clampi(d.x, 0, N_NODESC - 1) / BSZ], 1);
    atomicAdd(&h[clampi(d.y, 0, N_NODESC - 1) / BSZ], 1);
    atomicAdd(&h[clampi(d.z, 0, N_NODESC - 1) / BSZ], 1);
    atomicAdd(&h[clampi(d.w, 0, N_NODESC - 1) / BSZ], 1);
  }
  __syncthreads();
  for (int i = t; i < NBUCK; i += 256) if (h[i]) atomicAdd(&cc[i], h[i]);
}

// ---- scan 500 bucket counts (single block) ----
__global__ __launch_bounds__(512) void k_cscan(const int* __restrict__ cc,
                                               int* __restrict__ bstart,
                                               int* __restrict__ gcur) {
  __shared__ int sm[512];
  int t = threadIdx.x;
  int c = (t < NBUCK) ? cc[t] : 0;
  sm[t] = c;
  __syncthreads();
  for (int off = 1; off < 512; off <<= 1) {
    int v = sm[t];
    int a = (t >= off) ? sm[t - off] : 0;
    __syncthreads();
    sm[t] = v + a;
    __syncthreads();
  }
  if (t < NBUCK) { int e = sm[t] - c; bstart[t] = e; gcur[t] = e; }
}

// ---- coarse scatter: LDS counting-sort by bucket, contiguous run writes ----
__global__ __launch_bounds__(512) void k_csort(const int* __restrict__ ei,
                                               int* __restrict__ gcur,
                                               unsigned* __restrict__ cs) {
  __shared__ int h[NBUCK], lst[NBUCK], lcur[NBUCK], gb[NBUCK];
  __shared__ int sc[512];
  __shared__ unsigned sorted[P3_EDGES];
  __shared__ unsigned short sbk[P3_EDGES];
  int t = threadIdx.x;
  int base = blockIdx.x * P3_EDGES;
  for (int i = t; i < NBUCK; i += 512) h[i] = 0;
  __syncthreads();
  unsigned pk[8]; int bk[8];
  #pragma unroll
  for (int k = 0; k < 8; k++) {
    int idx = base + k * 512 + t;
    bk[k] = -1;
    if (idx < N_EDGESC) {
      int s = clampi(ei[idx], 0, N_NODESC - 1);
      int d = clampi(ei[N_EDGESC + idx], 0, N_NODESC - 1);
      int b = d / BSZ;
      pk[k] = (unsigned)s | ((unsigned)(d - b * BSZ) << 17);
      bk[k] = b;
      atomicAdd(&h[b], 1);
    }
  }
  __syncthreads();
  sc[t] = (t < NBUCK) ? h[t] : 0;
  __syncthreads();
  for (int off = 1; off < 512; off <<= 1) {
    int v = sc[t];
    int a = (t >= off) ? sc[t - off] : 0;
    __syncthreads();
    sc[t] = v + a;
    __syncthreads();
  }
  if (t < NBUCK) {
    int ex = sc[t] - h[t];
    lst[t] = ex; lcur[t] = ex;
    if (h[t]) gb[t] = atomicAdd(&gcur[t], h[t]);
  }
  __syncthreads();
  #pragma unroll
  for (int k = 0; k < 8; k++) if (bk[k] >= 0) {
    int p = atomicAdd(&lcur[bk[k]], 1);
    sorted[p] = pk[k];
    sbk[p] = (unsigned short)bk[k];
  }
  __syncthreads();
  int cnt = N_EDGESC - base; if (cnt > P3_EDGES) cnt = P3_EDGES;
  #pragma unroll
  for (int k = 0; k < 8; k++) {
    int i = k * 512 + t;
    if (i < cnt) {
      int b = sbk[i];
      cs[gb[b] + (i - lst[b])] = sorted[i];
    }
  }
}

// ---- K1: xw = x@W -> fp8 e4m3 table; a_src, a_dst fp32 ----
__global__ __launch_bounds__(256) void k1_transform(
    const unsigned short* __restrict__ x, const unsigned short* __restrict__ W,
    const unsigned short* __restrict__ attS, const unsigned short* __restrict__ attD,
    unsigned char* __restrict__ xw8, float* __restrict__ a_src,
    float* __restrict__ a_dst)
{
  __shared__ float Wsf[64 * 64];
  __shared__ float as_s[64];
  __shared__ float ad_s[64];
  int t = threadIdx.x;
  for (int i = t; i < 4096; i += 256) Wsf[i] = b2f(W[i]);
  if (t < 64) { as_s[t] = b2f(attS[t]); ad_s[t] = b2f(attD[t]); }
  __syncthreads();

  int g    = t & 3;
  int slot = t >> 2;
  int n0 = blockIdx.x * 256 + slot * 4;

  float acc[4][16];
  #pragma unroll
  for (int j = 0; j < 4; j++)
    #pragma unroll
    for (int c = 0; c < 16; c++) acc[j][c] = 0.f;

  const float4* Ws4 = (const float4*)Wsf;
  for (int i = 0; i < 8; i++) {
    float xu[4][8];
    #pragma unroll
    for (int j = 0; j < 4; j++) {
      int n = n0 + j;
      uint4 v = make_uint4(0u,0u,0u,0u);
      if (n < N_NODESC) v = ((const uint4*)(x + (size_t)n * 64))[i];
      unpack8(v, xu[j]);
    }
    #pragma unroll
    for (int u = 0; u < 8; u++) {
      int k = i * 8 + u;
      float4 w0 = Ws4[k * 16 + g * 4 + 0];
      float4 w1 = Ws4[k * 16 + g * 4 + 1];
      float4 w2 = Ws4[k * 16 + g * 4 + 2];
      float4 w3 = Ws4[k * 16 + g * 4 + 3];
      #pragma unroll
      for (int j = 0; j < 4; j++) {
        float xk = xu[j][u];
        acc[j][ 0] += xk * w0.x; acc[j][ 1] += xk * w0.y;
        acc[j][ 2] += xk * w0.z; acc[j][ 3] += xk * w0.w;
        acc[j][ 4] += xk * w1.x; acc[j][ 5] += xk * w1.y;
        acc[j][ 6] += xk * w1.z; acc[j][ 7] += xk * w1.w;
        acc[j][ 8] += xk * w2.x; acc[j][ 9] += xk * w2.y;
        acc[j][10] += xk * w2.z; acc[j][11] += xk * w2.w;
        acc[j][12] += xk * w3.x; acc[j][13] += xk * w3.y;
        acc[j][14] += xk * w3.z; acc[j][15] += xk * w3.w;
      }
    }
  }

  #pragma unroll
  for (int j = 0; j < 4; j++) {
    int n = n0 + j;
    if (n >= N_NODESC) break;
    union { unsigned u[4]; unsigned char b[16]; } pk;
    #pragma unroll
    for (int c = 0; c < 16; c++)
      pk.b[c] = (unsigned char)__hip_fp8_e4m3(acc[j][c]).__x;
    uint4 o; o.x = pk.u[0]; o.y = pk.u[1]; o.z = pk.u[2]; o.w = pk.u[3];
    *((uint4*)(xw8 + (size_t)n * 64 + g * 16)) = o;

    #pragma unroll
    for (int hl = 0; hl < 2; hl++) {
      int h = g * 2 + hl;
      float sa = 0.f, sd = 0.f;
      #pragma unroll
      for (int c = 0; c < 8; c++) {
        sa += acc[j][hl * 8 + c] * as_s[h * 8 + c];
        sd += acc[j][hl * 8 + c] * ad_s[h * 8 + c];
      }
      a_src[n * 8 + h] = sa;
      a_dst[n * 8 + h] = sd;
    }
  }
}

// ---- K_aggf: one 1024-thread WG per bucket (200 dsts).
// Phase 0: per-node counting sort of the bucket's edges into LDS.
// Phase 1: per-dst wave aggregation (batch-8, one exp per wave per 8 edges).
__global__ __launch_bounds__(1024) void k_aggf(
    const float* __restrict__ a_src, const float* __restrict__ a_dst,
    const unsigned char* __restrict__ xw8, const unsigned* __restrict__ cs,
    const int* __restrict__ cc, const int* __restrict__ bstart,
    const unsigned short* __restrict__ bias, unsigned short* __restrict__ nembh)
{
  __shared__ int lcnt[256], loff[256], lcur[256];
  __shared__ int ssrc[CAP];
  int t = threadIdx.x;
  int b = blockIdx.x;
  int base = bstart[b];
  int cnt  = cc[b];
  int scnt = cnt < CAP ? cnt : CAP;

  if (t < 256) lcnt[t] = 0;
  __syncthreads();
  for (int i = t; i < scnt; i += 1024) atomicAdd(&lcnt[cs[base + i] >> 17], 1);
  __syncthreads();
  if (t < 256) loff[t] = lcnt[t];
  __syncthreads();
  for (int off = 1; off < 256; off <<= 1) {
    int v = 0;
    if (t < 256) { v = loff[t]; if (t >= off) v += loff[t - off]; }
    __syncthreads();
    if (t < 256) loff[t] = v;
    __syncthreads();
  }
  if (t < 256) { int ex = loff[t] - lcnt[t]; loff[t] = ex; lcur[t] = ex; }
  __syncthreads();
  for (int i = t; i < scnt; i += 1024) {
    unsigned e = cs[base + i];
    int p = atomicAdd(&lcur[e >> 17], 1);
    ssrc[p] = (int)(e & 0x1FFFFu);
  }
  __syncthreads();

  int wv = t >> 6;
  int l  = t & 63;
  int H  = l >> 3;
  int hw = l & 7;

  for (int dl = wv; dl < BSZ; dl += 16) {
    int dst = b * BSZ + dl;
    float adH = a_dst[dst * 8 + H];
    float zs  = a_src[dst * 8 + H] + adH;
    float selfw = __expf(fmaxf(zs, 0.2f * zs));
    float acc = selfw * fp8tof(xw8[(size_t)dst * 64 + l]);
    float adW = a_dst[dst * 8 + hw];

    int beg = loff[dl];
    int end2 = beg + lcnt[dl];
    float lw = 0.f, lw2 = 0.f;

    for (int i = beg; i < end2; i += 8) {
      int idx = i + H;
      bool valid = idx < end2;
      int sv = ssrc[valid ? idx : end2 - 1];
      float av = a_src[sv * 8 + hw];
      float z = av + adW;
      float w = __expf(fmaxf(z, 0.2f * z));
      w = valid ? w : 0.f;
      lw += w;
      #pragma unroll
      for (int e = 0; e < 8; e++) {
        int   se = __builtin_amdgcn_readlane(sv, e * 8);
        float wb = __shfl(w, (e << 3) + H, 64);
        float xv = fp8tof(xw8[(size_t)se * 64 + l]);
        acc += wb * xv;
      }
    }

    // overflow edges beyond LDS capacity (statistically never taken)
    for (int i = CAP; i < cnt; i++) {
      unsigned e = cs[base + i];
      if ((int)(e >> 17) != dl) continue;
      int sv = (int)(e & 0x1FFFFu);
      float zz = a_src[sv * 8 + H] + adH;
      float w = __expf(fmaxf(zz, 0.2f * zz));
      lw2 += w;
      acc += w * fp8tof(xw8[(size_t)sv * 64 + l]);
    }

    lw += __shfl_xor(lw, 8, 64);
    lw += __shfl_xor(lw, 16, 64);
    lw += __shfl_xor(lw, 32, 64);
    float denom = selfw + __shfl(lw, H, 64) + lw2;

    float v = acc / denom + b2f(bias[l]);
    nembh[(size_t)dst * 64 + l] = f2b(v > 0.f ? v : 0.f);
  }
}

// ---- K6: padded gather from bf16 nemb -> fp32 out + seq_lengths tail ----
__global__ __launch_bounds__(256) void k6_gather(
    const unsigned short* __restrict__ nembh, const int* __restrict__ traj,
    const int* __restrict__ lens, float* __restrict__ out)
{
  int gid = blockIdx.x * 256 + threadIdx.x;
  if (gid < BATCHC * MAXLENC * 16) {
    int b = gid >> 15;
    int rem = gid & 32767;
    int l = rem >> 4;
    int ch = rem & 15;
    int len = clampi(lens[b], 0, MAXLENC);
    float4 val = make_float4(0.f, 0.f, 0.f, 0.f);
    if (l < len) {
      int node = clampi(traj[b * MAXLENC + l], 0, N_NODESC - 1);
      uint2 q = ((const uint2*)nembh)[(size_t)node * 16 + ch];
      val = make_float4(b2f((unsigned short)(q.x & 0xffff)),
                        b2f((unsigned short)(q.x >> 16)),
                        b2f((unsigned short)(q.y & 0xffff)),
                        b2f((unsigned short)(q.y >> 16)));
    }
    ((float4*)out)[gid] = val;
  }
  if (gid < BATCHC) {
    out[(size_t)BATCHC * MAXLENC * FEATC + gid] = (float)lens[gid];
  }
}

extern "C" void kernel_launch(void* const* d_in, const int* in_sizes, int n_in,
                              void* d_out, int out_size, void* d_ws, size_t ws_size,
                              hipStream_t stream) {
  const unsigned short* x    = (const unsigned short*)d_in[0];
  const unsigned short* W    = (const unsigned short*)d_in[1];
  const unsigned short* attS = (const unsigned short*)d_in[2];
  const unsigned short* attD = (const unsigned short*)d_in[3];
  const unsigned short* bias = (const unsigned short*)d_in[4];
  const int* ei   = (const int*)d_in[5];
  const int* traj = (const int*)d_in[6];
  const int* lens = (const int*)d_in[7];
  float* out = (float*)d_out;

  // workspace (float units, max 8.3M floats = 33.2 MB; well under proven size):
  //  [0, 1.6M)        xw fp8 (6.4M bytes)
  //  [3.2M, 4.0M)     a_src
  //  [4.0M, 4.8M)     a_dst
  //  [4.9M, +512)     ccounts (500)
  //  [+512, +1024)    bstart
  //  [+1024, +1536)   gcur
  //  [5.0M, 6.6M)     cs (packed uint, 1.6M)
  //  [6.7M, 8.3M)     nemb bf16 (6.4M ushort)
  float* F = (float*)d_ws;
  unsigned char* xw8 = (unsigned char*)d_ws;
  float* a_src   = F + 3200000;
  float* a_dst   = F + 4000000;
  int* ccounts   = (int*)(F + 4900000);
  int* bstart    = (int*)(F + 4900000) + 512;
  int* gcur      = (int*)(F + 4900000) + 1024;
  unsigned* cs   = (unsigned*)(F + 5000000);
  unsigned short* nembh = (unsigned short*)(F + 6700000);

  hipMemsetAsync(ccounts, 0, NBUCK * sizeof(int), stream);
  k_chist<<<(N_EDGESC / 4 + 255) / 256, 256, 0, stream>>>(ei, ccounts);
  k_cscan<<<1, 512, 0, stream>>>(ccounts, bstart, gcur);
  k_csort<<<(N_EDGESC + P3_EDGES - 1) / P3_EDGES, 512, 0, stream>>>(ei, gcur, cs);
  k1_transform<<<(N_NODESC + 255) / 256, 256, 0, stream>>>(x, W, attS, attD, xw8, a_src, a_dst);
  k_aggf<<<NBUCK, 1024, 0, stream>>>(a_src, a_dst, xw8, cs, ccounts, bstart, bias, nembh);
  k6_gather<<<(BATCHC * MAXLENC * 16 + 255) / 256, 256, 0, stream>>>(nembh, traj, lens, out);
}

// Round 11
// 200.393 us; speedup vs baseline: 15.6850x; 1.0938x over previous
//
#include <hip/hip_runtime.h>
#include <hip/hip_bf16.h>
#include <hip/hip_fp8.h>
#include <hip/hip_fp16.h>

#define N_NODESC 100000
#define N_EDGESC 1600000
#define FEATC 64
#define HEADSC 8
#define BATCHC 64
#define MAXLENC 2048
#define NBUCK 500          // 500 buckets x exactly 200 dst nodes
#define BSZ 200
#define CAP 6144           // LDS edge capacity per bucket (mean 3200, sigma ~57)
#define P3_EDGES 8192      // edges per k_csort workgroup (1024 thr x 8)
#define K1B 391            // k_pre blocks doing the node transform

__device__ __forceinline__ float b2f(unsigned short u){
  union { unsigned u; float f; } c; c.u = ((unsigned)u) << 16; return c.f;
}
__device__ __forceinline__ unsigned short f2b(float f){
  union { float f; unsigned u; } c; c.f = f;
  unsigned r = c.u + 0x7fffu + ((c.u >> 16) & 1u);
  return (unsigned short)(r >> 16);
}
__device__ __forceinline__ int clampi(int v, int lo, int hi){
  return v < lo ? lo : (v > hi ? hi : v);
}
__device__ __forceinline__ void unpack8(uint4 v, float* o){
  o[0] = b2f((unsigned short)(v.x & 0xffff)); o[1] = b2f((unsigned short)(v.x >> 16));
  o[2] = b2f((unsigned short)(v.y & 0xffff)); o[3] = b2f((unsigned short)(v.y >> 16));
  o[4] = b2f((unsigned short)(v.z & 0xffff)); o[5] = b2f((unsigned short)(v.z >> 16));
  o[6] = b2f((unsigned short)(v.w & 0xffff)); o[7] = b2f((unsigned short)(v.w >> 16));
}
__device__ __forceinline__ float fp8tof(unsigned char b){
  __hip_fp8_e4m3 q; q.__x = (__hip_fp8_storage_t)b; return (float)q;
}

// ---- K_pre: heterogeneous grid. Blocks [0,K1B): xw=x@W -> fp8 + a_src(fp16)
// + a_dst(fp32). Blocks [K1B,..): coarse 500-bin histogram of dst. ----
__global__ __launch_bounds__(256) void k_pre(
    const unsigned short* __restrict__ x, const unsigned short* __restrict__ W,
    const unsigned short* __restrict__ attS, const unsigned short* __restrict__ attD,
    const int* __restrict__ ei,
    unsigned char* __restrict__ xw8, __half* __restrict__ a_srch,
    float* __restrict__ a_dst, int* __restrict__ cc)
{
  __shared__ float Wsf[64 * 64];
  __shared__ float as_s[64];
  __shared__ float ad_s[64];
  __shared__ int hh[NBUCK];
  int t = threadIdx.x;

  if (blockIdx.x >= K1B) {
    // ---- coarse histogram part ----
    for (int i = t; i < NBUCK; i += 256) hh[i] = 0;
    __syncthreads();
    int g = (blockIdx.x - K1B) * 256 + t;
    if (g < N_EDGESC / 4) {
      int4 d = ((const int4*)(ei + N_EDGESC))[g];
      atomicAdd(&hh[clampi(d.x, 0, N_NODESC - 1) / BSZ], 1);
      atomicAdd(&hh[clampi(d.y, 0, N_NODESC - 1) / BSZ], 1);
      atomicAdd(&hh[clampi(d.z, 0, N_NODESC - 1) / BSZ], 1);
      atomicAdd(&hh[clampi(d.w, 0, N_NODESC - 1) / BSZ], 1);
    }
    __syncthreads();
    for (int i = t; i < NBUCK; i += 256) if (hh[i]) atomicAdd(&cc[i], hh[i]);
    return;
  }

  // ---- node transform part ----
  for (int i = t; i < 4096; i += 256) Wsf[i] = b2f(W[i]);
  if (t < 64) { as_s[t] = b2f(attS[t]); ad_s[t] = b2f(attD[t]); }
  __syncthreads();

  int g    = t & 3;
  int slot = t >> 2;
  int n0 = blockIdx.x * 256 + slot * 4;

  float acc[4][16];
  #pragma unroll
  for (int j = 0; j < 4; j++)
    #pragma unroll
    for (int c = 0; c < 16; c++) acc[j][c] = 0.f;

  const float4* Ws4 = (const float4*)Wsf;
  for (int i = 0; i < 8; i++) {
    float xu[4][8];
    #pragma unroll
    for (int j = 0; j < 4; j++) {
      int n = n0 + j;
      uint4 v = make_uint4(0u,0u,0u,0u);
      if (n < N_NODESC) v = ((const uint4*)(x + (size_t)n * 64))[i];
      unpack8(v, xu[j]);
    }
    #pragma unroll
    for (int u = 0; u < 8; u++) {
      int k = i * 8 + u;
      float4 w0 = Ws4[k * 16 + g * 4 + 0];
      float4 w1 = Ws4[k * 16 + g * 4 + 1];
      float4 w2 = Ws4[k * 16 + g * 4 + 2];
      float4 w3 = Ws4[k * 16 + g * 4 + 3];
      #pragma unroll
      for (int j = 0; j < 4; j++) {
        float xk = xu[j][u];
        acc[j][ 0] += xk * w0.x; acc[j][ 1] += xk * w0.y;
        acc[j][ 2] += xk * w0.z; acc[j][ 3] += xk * w0.w;
        acc[j][ 4] += xk * w1.x; acc[j][ 5] += xk * w1.y;
        acc[j][ 6] += xk * w1.z; acc[j][ 7] += xk * w1.w;
        acc[j][ 8] += xk * w2.x; acc[j][ 9] += xk * w2.y;
        acc[j][10] += xk * w2.z; acc[j][11] += xk * w2.w;
        acc[j][12] += xk * w3.x; acc[j][13] += xk * w3.y;
        acc[j][14] += xk * w3.z; acc[j][15] += xk * w3.w;
      }
    }
  }

  #pragma unroll
  for (int j = 0; j < 4; j++) {
    int n = n0 + j;
    if (n >= N_NODESC) break;
    union { unsigned u[4]; unsigned char b[16]; } pk;
    #pragma unroll
    for (int c = 0; c < 16; c++)
      pk.b[c] = (unsigned char)__hip_fp8_e4m3(acc[j][c]).__x;
    uint4 o; o.x = pk.u[0]; o.y = pk.u[1]; o.z = pk.u[2]; o.w = pk.u[3];
    *((uint4*)(xw8 + (size_t)n * 64 + g * 16)) = o;

    #pragma unroll
    for (int hl = 0; hl < 2; hl++) {
      int h = g * 2 + hl;
      float sa = 0.f, sd = 0.f;
      #pragma unroll
      for (int c = 0; c < 8; c++) {
        sa += acc[j][hl * 8 + c] * as_s[h * 8 + c];
        sd += acc[j][hl * 8 + c] * ad_s[h * 8 + c];
      }
      a_srch[n * 8 + h] = __float2half(sa);
      a_dst[n * 8 + h] = sd;
    }
  }
}

// ---- coarse scatter (1024 thr, 8192 edges/wg): self-scan of cc -> bstart,
// LDS counting-sort by bucket, contiguous run writes via zero-based gcur ----
__global__ __launch_bounds__(1024) void k_csort(const int* __restrict__ ei,
                                                const int* __restrict__ cc,
                                                int* __restrict__ gcur,
                                                unsigned* __restrict__ cs) {
  __shared__ int bst[512];
  __shared__ int h[NBUCK], lst[NBUCK], lcur[NBUCK], gb[NBUCK];
  __shared__ int sc[512];
  __shared__ unsigned sorted[P3_EDGES];
  __shared__ unsigned short sbk[P3_EDGES];
  int t = threadIdx.x;
  int base = blockIdx.x * P3_EDGES;
  for (int i = t; i < NBUCK; i += 1024) h[i] = 0;
  int myc = 0;
  if (t < 512) { myc = (t < NBUCK) ? cc[t] : 0; bst[t] = myc; }
  __syncthreads();
  for (int off = 1; off < 512; off <<= 1) {
    int v = 0;
    if (t < 512) { v = bst[t]; if (t >= off) v += bst[t - off]; }
    __syncthreads();
    if (t < 512) bst[t] = v;
    __syncthreads();
  }
  unsigned pk[8]; int bk[8];
  #pragma unroll
  for (int k = 0; k < 8; k++) {
    int idx = base + k * 1024 + t;
    bk[k] = -1;
    if (idx < N_EDGESC) {
      int s = clampi(ei[idx], 0, N_NODESC - 1);
      int d = clampi(ei[N_EDGESC + idx], 0, N_NODESC - 1);
      int b = d / BSZ;
      pk[k] = (unsigned)s | ((unsigned)(d - b * BSZ) << 17);
      bk[k] = b;
      atomicAdd(&h[b], 1);
    }
  }
  __syncthreads();
  if (t < 512) sc[t] = (t < NBUCK) ? h[t] : 0;
  __syncthreads();
  for (int off = 1; off < 512; off <<= 1) {
    int v = 0;
    if (t < 512) { v = sc[t]; if (t >= off) v += sc[t - off]; }
    __syncthreads();
    if (t < 512) sc[t] = v;
    __syncthreads();
  }
  if (t < NBUCK) {
    int ex = sc[t] - h[t];
    lst[t] = ex; lcur[t] = ex;
    if (h[t]) gb[t] = (bst[t] - myc) + atomicAdd(&gcur[t], h[t]);
  }
  __syncthreads();
  #pragma unroll
  for (int k = 0; k < 8; k++) if (bk[k] >= 0) {
    int p = atomicAdd(&lcur[bk[k]], 1);
    sorted[p] = pk[k];
    sbk[p] = (unsigned short)bk[k];
  }
  __syncthreads();
  int cnt = N_EDGESC - base; if (cnt > P3_EDGES) cnt = P3_EDGES;
  #pragma unroll
  for (int k = 0; k < 8; k++) {
    int i = k * 1024 + t;
    if (i < cnt) {
      int b = sbk[i];
      cs[gb[b] + (i - lst[b])] = sorted[i];
    }
  }
}

// ---- K_aggf: one 1024-thread WG per bucket (200 dsts). Self-scans cc for
// its base; counting-sorts its edges into LDS (cs entries cached in regs);
// per-dst wave aggregation with one exp per wave per 8 edges. ----
__global__ __launch_bounds__(1024) void k_aggf(
    const __half* __restrict__ a_srch, const float* __restrict__ a_dst,
    const unsigned char* __restrict__ xw8, const unsigned* __restrict__ cs,
    const int* __restrict__ cc,
    const unsigned short* __restrict__ bias, unsigned short* __restrict__ nembh)
{
  __shared__ int bsc[512];
  __shared__ int lcnt[256], loff[256], lcur[256];
  __shared__ int ssrc[CAP];
  __shared__ int sbase, scnt0;
  int t = threadIdx.x;
  int b = blockIdx.x;

  int myc = 0;
  if (t < 512) { myc = (t < NBUCK) ? cc[t] : 0; bsc[t] = myc; }
  __syncthreads();
  for (int off = 1; off < 512; off <<= 1) {
    int v = 0;
    if (t < 512) { v = bsc[t]; if (t >= off) v += bsc[t - off]; }
    __syncthreads();
    if (t < 512) bsc[t] = v;
    __syncthreads();
  }
  if (t == b) { sbase = bsc[t] - myc; scnt0 = myc; }
  if (t < 256) lcnt[t] = 0;
  __syncthreads();
  int base = sbase;
  int cnt  = scnt0;
  int scnt = cnt < CAP ? cnt : CAP;

  unsigned ce[6];
  #pragma unroll
  for (int j = 0; j < 6; j++) {
    int i = t + j * 1024;
    if (i < scnt) { ce[j] = cs[base + i]; atomicAdd(&lcnt[ce[j] >> 17], 1); }
  }
  __syncthreads();
  if (t < 256) loff[t] = lcnt[t];
  __syncthreads();
  for (int off = 1; off < 256; off <<= 1) {
    int v = 0;
    if (t < 256) { v = loff[t]; if (t >= off) v += loff[t - off]; }
    __syncthreads();
    if (t < 256) loff[t] = v;
    __syncthreads();
  }
  if (t < 256) { int ex = loff[t] - lcnt[t]; loff[t] = ex; lcur[t] = ex; }
  __syncthreads();
  #pragma unroll
  for (int j = 0; j < 6; j++) {
    int i = t + j * 1024;
    if (i < scnt) {
      int p = atomicAdd(&lcur[ce[j] >> 17], 1);
      ssrc[p] = (int)(ce[j] & 0x1FFFFu);
    }
  }
  __syncthreads();

  int wv = t >> 6;
  int l  = t & 63;
  int H  = l >> 3;
  int hw = l & 7;

  for (int dl = wv; dl < BSZ; dl += 16) {
    int dst = b * BSZ + dl;
    float adH = a_dst[dst * 8 + H];
    float zs  = __half2float(a_srch[dst * 8 + H]) + adH;
    float selfw = __expf(fmaxf(zs, 0.2f * zs));
    float acc = selfw * fp8tof(xw8[(size_t)dst * 64 + l]);
    float adW = a_dst[dst * 8 + hw];

    int beg = loff[dl];
    int end2 = beg + lcnt[dl];
    float lw = 0.f, lw2 = 0.f;

    for (int i = beg; i < end2; i += 8) {
      int idx = i + H;
      bool valid = idx < end2;
      int sv = ssrc[valid ? idx : end2 - 1];
      float av = __half2float(a_srch[sv * 8 + hw]);
      float z = av + adW;
      float w = __expf(fmaxf(z, 0.2f * z));
      w = valid ? w : 0.f;
      lw += w;
      #pragma unroll
      for (int e = 0; e < 8; e++) {
        int   se = __builtin_amdgcn_readlane(sv, e * 8);
        float wb = __shfl(w, (e << 3) + H, 64);
        float xv = fp8tof(xw8[(size_t)se * 64 + l]);
        acc += wb * xv;
      }
    }

    // overflow edges beyond LDS capacity (statistically never taken)
    for (int i = CAP; i < cnt; i++) {
      unsigned e = cs[base + i];
      if ((int)(e >> 17) != dl) continue;
      int sv = (int)(e & 0x1FFFFu);
      float zz = __half2float(a_srch[sv * 8 + H]) + adH;
      float w = __expf(fmaxf(zz, 0.2f * zz));
      lw2 += w;
      acc += w * fp8tof(xw8[(size_t)sv * 64 + l]);
    }

    lw += __shfl_xor(lw, 8, 64);
    lw += __shfl_xor(lw, 16, 64);
    lw += __shfl_xor(lw, 32, 64);
    float denom = selfw + __shfl(lw, H, 64) + lw2;

    float v = acc / denom + b2f(bias[l]);
    nembh[(size_t)dst * 64 + l] = f2b(v > 0.f ? v : 0.f);
  }
}

// ---- K6: padded gather from bf16 nemb -> fp32 out + seq_lengths tail ----
__global__ __launch_bounds__(256) void k6_gather(
    const unsigned short* __restrict__ nembh, const int* __restrict__ traj,
    const int* __restrict__ lens, float* __restrict__ out)
{
  int gid = blockIdx.x * 256 + threadIdx.x;
  if (gid < BATCHC * MAXLENC * 16) {
    int b = gid >> 15;
    int rem = gid & 32767;
    int l = rem >> 4;
    int ch = rem & 15;
    int len = clampi(lens[b], 0, MAXLENC);
    float4 val = make_float4(0.f, 0.f, 0.f, 0.f);
    if (l < len) {
      int node = clampi(traj[b * MAXLENC + l], 0, N_NODESC - 1);
      uint2 q = ((const uint2*)nembh)[(size_t)node * 16 + ch];
      val = make_float4(b2f((unsigned short)(q.x & 0xffff)),
                        b2f((unsigned short)(q.x >> 16)),
                        b2f((unsigned short)(q.y & 0xffff)),
                        b2f((unsigned short)(q.y >> 16)));
    }
    ((float4*)out)[gid] = val;
  }
  if (gid < BATCHC) {
    out[(size_t)BATCHC * MAXLENC * FEATC + gid] = (float)lens[gid];
  }
}

extern "C" void kernel_launch(void* const* d_in, const int* in_sizes, int n_in,
                              void* d_out, int out_size, void* d_ws, size_t ws_size,
                              hipStream_t stream) {
  const unsigned short* x    = (const unsigned short*)d_in[0];
  const unsigned short* W    = (const unsigned short*)d_in[1];
  const unsigned short* attS = (const unsigned short*)d_in[2];
  const unsigned short* attD = (const unsigned short*)d_in[3];
  const unsigned short* bias = (const unsigned short*)d_in[4];
  const int* ei   = (const int*)d_in[5];
  const int* traj = (const int*)d_in[6];
  const int* lens = (const int*)d_in[7];
  float* out = (float*)d_out;

  // workspace (float units, max 9.9M floats = 39.6 MB; under proven size):
  //  [0, 1.6M)        xw fp8 (6.4M bytes)
  //  [3.2M, 3.6M)     a_src fp16 (800k half)
  //  [4.0M, 4.8M)     a_dst fp32
  //  [4.9M, +512)     ccounts (500)
  //  [+512, +1024)    gcur (500, zero-based)   -- one memset covers both
  //  [5.0M, 6.6M)     cs (packed uint, 1.6M)
  //  [6.7M, 9.9M)     nemb bf16 (6.4M ushort)
  float* F = (float*)d_ws;
  unsigned char* xw8 = (unsigned char*)d_ws;
  __half* a_srch = (__half*)(F + 3200000);
  float* a_dst   = F + 4000000;
  int* ccounts   = (int*)(F + 4900000);
  int* gcur      = (int*)(F + 4900000) + 512;
  unsigned* cs   = (unsigned*)(F + 5000000);
  unsigned short* nembh = (unsigned short*)(F + 6700000);

  hipMemsetAsync(ccounts, 0, 1024 * sizeof(int), stream);
  k_pre<<<K1B + (N_EDGESC / 4 + 255) / 256, 256, 0, stream>>>(
      x, W, attS, attD, ei, xw8, a_srch, a_dst, ccounts);
  k_csort<<<(N_EDGESC + P3_EDGES - 1) / P3_EDGES, 1024, 0, stream>>>(ei, ccounts, gcur, cs);
  k_aggf<<<NBUCK, 1024, 0, stream>>>(a_srch, a_dst, xw8, cs, ccounts, bias, nembh);
  k6_gather<<<(BATCHC * MAXLENC * 16 + 255) / 256, 256, 0, stream>>>(nembh, traj, lens, out);
}